// Round 14
// baseline (117.258 us; speedup 1.0000x reference)
//
#include <hip/hip_runtime.h>
#include <math.h>

#define CC 256
#define CI 128
#define NN 8192
#define MM 2048
#define NSPLIT 4
#define KSPAN 512
#define KT 64
#define NCH 8
#define SUBC 20.0f

typedef __attribute__((ext_vector_type(8))) short bf16x8;
typedef __attribute__((ext_vector_type(4))) float f32x4;

// ws byte offsets
#define OFF_XT      0u
#define OFF_WQH     8388608u
#define OFF_WQL     8585216u
#define OFF_WOH     8781824u
#define OFF_WOL     8847360u
#define OFF_THETA16 8912896u
#define OFF_PHI16   13107200u
#define OFF_G16     14155776u
#define OFF_YP      15204352u
#define OFF_LBUF    48758784u
#define OFF_PSUM    49020928u
#define OFF_PSQ     49283072u
#define OFF_STAT    49545216u

static __device__ __forceinline__ unsigned short f2bfbits(float x) {
    unsigned u = __builtin_bit_cast(unsigned, x);
    u = u + 0x7fffu + ((u >> 16) & 1u);
    return (unsigned short)(u >> 16);
}
static __device__ __forceinline__ float bf2f(unsigned short h) {
    return __builtin_bit_cast(float, ((unsigned)h) << 16);
}
static __device__ __forceinline__ void gll16(const void* g, void* l) {
    __builtin_amdgcn_global_load_lds(
        (const __attribute__((address_space(1))) unsigned int*)g,
        (__attribute__((address_space(3))) unsigned int*)l, 16, 0, 0);
}

// ---------------------------------------------------------------------------
// K0: x fp32 [b][c][n] -> xT bf16 [b][n][c]  (+ fused weight hi/lo prep)
// grid (128, 4, 2), 256 thr   [R8, proven]
// ---------------------------------------------------------------------------
__global__ __launch_bounds__(256) void k_xtprep(
    const float* __restrict__ x,
    const float* __restrict__ tw, const float* __restrict__ pw,
    const float* __restrict__ gw, const float* __restrict__ ow,
    unsigned short* __restrict__ xT,
    unsigned short* __restrict__ wqh, unsigned short* __restrict__ wql,
    unsigned short* __restrict__ woh, unsigned short* __restrict__ wol)
{
    __shared__ float Xl[64 * 68];
    const int nb = blockIdx.x * 64, cb = blockIdx.y * 64, b = blockIdx.z;
    const int t = threadIdx.x;

    {
        const int fid = (((blockIdx.z * 4 + blockIdx.y) * 128 + blockIdx.x) * 256) + t;
        if (fid < 98304) {
            const float v = (fid < 32768) ? tw[fid] : (fid < 65536) ? pw[fid - 32768] : gw[fid - 65536];
            const unsigned short h = f2bfbits(v);
            wqh[fid] = h;
            wql[fid] = f2bfbits(v - bf2f(h));
        } else if (fid < 131072) {
            const int j = fid - 98304;
            const float v = ow[j];
            const unsigned short h = f2bfbits(v);
            woh[j] = h;
            wol[j] = f2bfbits(v - bf2f(h));
        }
    }

    const float* xb = x + ((size_t)b * CC + cb) * NN + nb;
    {
        const int cl = t >> 4, n4 = (t & 15) * 4;
#pragma unroll
        for (int i = 0; i < 4; ++i)
            *(float4*)&Xl[(cl + i * 16) * 68 + n4] =
                *(const float4*)&xb[(size_t)(cl + i * 16) * NN + n4];
    }
    __syncthreads();
    const int n = t >> 2, c0 = (t & 3) * 16;
    unsigned short v[16];
#pragma unroll
    for (int j = 0; j < 16; ++j) v[j] = f2bfbits(Xl[(c0 + j) * 68 + n]);
    unsigned short* dst = xT + ((size_t)b * NN + nb + n) * CC + cb + c0;
    *(uint4*)dst = *(uint4*)&v[0];
    *(uint4*)(dst + 8) = *(uint4*)&v[8];
}

// ---------------------------------------------------------------------------
// K1: theta/phi/g via bf16 MFMA, split-W  [R8, proven]
// grid (128, 3, 2), 256 thr
// ---------------------------------------------------------------------------
__global__ __launch_bounds__(256) void k_qkvm(
    const unsigned short* __restrict__ xT,
    const unsigned short* __restrict__ wqh, const unsigned short* __restrict__ wql,
    const float* __restrict__ tb, const float* __restrict__ pb, const float* __restrict__ gb,
    unsigned short* __restrict__ thetaT, unsigned short* __restrict__ phiT,
    unsigned short* __restrict__ gT)
{
    __shared__ unsigned short park[64 * 136];
    const int nt_ = blockIdx.x, sel = blockIdx.y, b = blockIdx.z;
    const int nb = nt_ * 64;
    const int tid = threadIdx.x, wave = tid >> 6, lane = tid & 63;
    const int lq = lane & 15, G = lane >> 4;
    const int obase = wave * 32;
    const int orow = sel * 128 + obase;
    const float* bias = (sel == 0) ? tb : (sel == 1) ? pb : gb;

    f32x4 acc[2][4];
#pragma unroll
    for (int ot = 0; ot < 2; ++ot)
#pragma unroll
        for (int nt = 0; nt < 4; ++nt) acc[ot][nt] = (f32x4){0.f, 0.f, 0.f, 0.f};

    const unsigned short* xrow = xT + ((size_t)b * NN + nb) * CC;
#pragma unroll
    for (int kc = 0; kc < 8; ++kc) {
        bf16x8 wh[2], wl[2], xf[4];
#pragma unroll
        for (int ot = 0; ot < 2; ++ot) {
            const size_t wr = (size_t)(orow + ot * 16 + lq) * CC + kc * 32 + G * 8;
            wh[ot] = *(const bf16x8*)(wqh + wr);
            wl[ot] = *(const bf16x8*)(wql + wr);
        }
#pragma unroll
        for (int nt = 0; nt < 4; ++nt)
            xf[nt] = *(const bf16x8*)(xrow + (size_t)(nt * 16 + lq) * CC + kc * 32 + G * 8);
#pragma unroll
        for (int ot = 0; ot < 2; ++ot)
#pragma unroll
            for (int nt = 0; nt < 4; ++nt) {
                acc[ot][nt] = __builtin_amdgcn_mfma_f32_16x16x32_bf16(wh[ot], xf[nt], acc[ot][nt], 0, 0, 0);
                acc[ot][nt] = __builtin_amdgcn_mfma_f32_16x16x32_bf16(wl[ot], xf[nt], acc[ot][nt], 0, 0, 0);
            }
    }
#pragma unroll
    for (int ot = 0; ot < 2; ++ot) {
        const float4 bv = *(const float4*)&bias[obase + ot * 16 + G * 4];
#pragma unroll
        for (int nt = 0; nt < 4; ++nt) {
            acc[ot][nt][0] += bv.x; acc[ot][nt][1] += bv.y;
            acc[ot][nt][2] += bv.z; acc[ot][nt][3] += bv.w;
        }
    }

    if (sel == 0) {
#pragma unroll
        for (int ot = 0; ot < 2; ++ot)
#pragma unroll
            for (int nt = 0; nt < 4; ++nt) {
                unsigned short pk[4];
#pragma unroll
                for (int r = 0; r < 4; ++r) pk[r] = f2bfbits(acc[ot][nt][r]);
                const int n = nb + nt * 16 + lq;
                const int ci = obase + ot * 16 + G * 4;
                *(uint2*)&thetaT[((size_t)b * NN + n) * CI + ci] = *(uint2*)pk;
            }
    } else {
#pragma unroll
        for (int ot = 0; ot < 2; ++ot)
#pragma unroll
            for (int nt = 0; nt < 4; ++nt) {
                unsigned short pk[4];
#pragma unroll
                for (int r = 0; r < 4; ++r) pk[r] = f2bfbits(acc[ot][nt][r]);
                const int n = nt * 16 + lq;
                const int o = obase + ot * 16 + G * 4;
                *(uint2*)&park[n * 136 + o] = *(uint2*)pk;
            }
        __syncthreads();
        const int tfrm = nb >> 10, h0 = (nb >> 5) & 31;
        const int mb = tfrm * 256 + (h0 >> 1) * 16;
        if (sel == 1) {
            for (int idx = tid; idx < 2048; idx += 256) {
                const int o = idx & 127, m = idx >> 7;
                const float v = fmaxf(
                    fmaxf(bf2f(park[(2 * m) * 136 + o]), bf2f(park[(2 * m + 1) * 136 + o])),
                    fmaxf(bf2f(park[(32 + 2 * m) * 136 + o]), bf2f(park[(33 + 2 * m) * 136 + o])));
                phiT[((size_t)b * MM + mb + m) * CI + o] = f2bfbits(v);
            }
        } else {
            for (int idx = tid; idx < 2048; idx += 256) {
                const int o = idx >> 4, m = idx & 15;
                const float v = fmaxf(
                    fmaxf(bf2f(park[(2 * m) * 136 + o]), bf2f(park[(2 * m + 1) * 136 + o])),
                    fmaxf(bf2f(park[(32 + 2 * m) * 136 + o]), bf2f(park[(33 + 2 * m) * 136 + o])));
                gT[((size_t)b * CI + o) * MM + mb + m] = f2bfbits(v);
            }
        }
    }
}

// ---------------------------------------------------------------------------
// K2: flash attention, static-max, counted vmcnt  [R12 kernel, NSPLIT=4]
// grid (64 qblk, 4 s, 2 b) = 512 blocks (2/CU, 4 waves/SIMD), 512 thr,
// 16 q/wave, KT=64 dbuf, NCH=8.
// ---------------------------------------------------------------------------
__global__ __launch_bounds__(512, 4) void k_attn(
    const unsigned short* __restrict__ thetaT,
    const unsigned short* __restrict__ phiT,
    const unsigned short* __restrict__ gT,
    unsigned short* __restrict__ yp,
    float* __restrict__ lbuf)
{
    __shared__ __align__(16) char smem[73728];  // 2 x (phi 16K + g 16K) + P 8K
    const int tid  = threadIdx.x;
    const int wave = tid >> 6;
    const int lane = tid & 63;
    const int lq = lane & 15, G = lane >> 4;
    const int qblk = blockIdx.x, s = blockIdx.y, b = blockIdx.z;
    const int qbase = qblk * 128 + wave * 16;
    const int koff0 = s * KSPAN;

    bf16x8 tf[4];
    {
        const size_t row = (size_t)b * NN + qbase + lq;
#pragma unroll
        for (int D = 0; D < 4; ++D)
            tf[D] = *(const bf16x8*)(thetaT + row * CI + D * 32 + G * 8);
    }

    const char* phiSrc = (const char*)(phiT + (size_t)b * MM * CI);
    const char* gSrc   = (const char*)(gT   + (size_t)b * CI * MM);
    int pk[2], pco[2];
#pragma unroll
    for (int i = 0; i < 2; ++i) {
        pk[i]  = wave * 8 + i * 4 + (lane >> 4);
        pco[i] = ((lane & 15) ^ (pk[i] & 7)) << 4;
    }
    const int gr0 = wave * 16 + (lane >> 3);
    const int u_  = lane & 7;
    const int gu  = (u_ & 4) | ((u_ & 3) ^ (gr0 & 3));

    auto STAGE = [&](int buf, int koff) {
        char* pl = smem + buf * 32768 + wave * 2048;
        char* gl = smem + buf * 32768 + 16384 + wave * 2048;
#pragma unroll
        for (int i = 0; i < 2; ++i) {
            gll16(phiSrc + (size_t)(koff + pk[i]) * 256 + pco[i], pl + i * 1024);
            gll16(gSrc + (size_t)(gr0 + i * 8) * 4096 + (size_t)koff * 2 + gu * 16, gl + i * 1024);
        }
    };

    f32x4 yacc[8];
#pragma unroll
    for (int c = 0; c < 8; ++c) yacc[c] = (f32x4){0.f, 0.f, 0.f, 0.f};
    float lreg = 0.f;

    STAGE(0, koff0);

    char* pP = smem + 65536 + wave * 1024;
    const int swq = (lq & 3) << 4;
    const int swk = (lq & 7) << 4;

    for (int ch = 0; ch < NCH; ++ch) {
        const int cur = ch & 1;
        if (ch < NCH - 1) {
            STAGE(cur ^ 1, koff0 + (ch + 1) * KT);
            // 8 outstanding: wait for the 4 oldest (buf[cur]); 4 newest stay in flight
            asm volatile("s_waitcnt vmcnt(4)" ::: "memory");
        } else {
            asm volatile("s_waitcnt vmcnt(0)" ::: "memory");
        }
        __builtin_amdgcn_s_barrier();   // all waves' buf[cur] loads landed

        const char* pbuf = smem + cur * 32768;
        const char* gbuf = smem + cur * 32768 + 16384;

#pragma unroll
        for (int t2 = 0; t2 < 2; ++t2) {
            f32x4 sacc[2];
            sacc[0] = (f32x4){0.f, 0.f, 0.f, 0.f};
            sacc[1] = (f32x4){0.f, 0.f, 0.f, 0.f};
            __builtin_amdgcn_s_setprio(1);
#pragma unroll
            for (int D = 0; D < 4; ++D) {
                const int co = (((D * 4 + G) << 4) ^ swk);
                const bf16x8 a0 = *(const bf16x8*)(pbuf + (t2 * 32 + lq) * 256 + co);
                const bf16x8 a1 = *(const bf16x8*)(pbuf + (t2 * 32 + 16 + lq) * 256 + co);
                sacc[0] = __builtin_amdgcn_mfma_f32_16x16x32_bf16(a0, tf[D], sacc[0], 0, 0, 0);
                sacc[1] = __builtin_amdgcn_mfma_f32_16x16x32_bf16(a1, tf[D], sacc[1], 0, 0, 0);
            }
            __builtin_amdgcn_s_setprio(0);

            float p[8];
#pragma unroll
            for (int ks = 0; ks < 2; ++ks)
#pragma unroll
                for (int r = 0; r < 4; ++r) {
                    const float e = __expf(sacc[ks][r] - SUBC);
                    p[ks * 4 + r] = e;
                    lreg += e;
                }
#pragma unroll
            for (int ks = 0; ks < 2; ++ks)
#pragma unroll
                for (int r2 = 0; r2 < 2; ++r2) {
                    const unsigned w = (unsigned)f2bfbits(p[ks * 4 + r2 * 2]) |
                                       ((unsigned)f2bfbits(p[ks * 4 + r2 * 2 + 1]) << 16);
                    const int byt = (ks * 32 + G * 8 + r2 * 4) ^ swq;
                    *(unsigned*)(pP + lq * 64 + byt) = w;
                }

            const bf16x8 pf = *(const bf16x8*)(pP + lq * 64 + ((G * 16) ^ swq));
            __builtin_amdgcn_s_setprio(1);
#pragma unroll
            for (int c = 0; c < 8; ++c) {
                const int row = c * 16 + lq;
                const bf16x8 gf = *(const bf16x8*)(gbuf + row * 128 + t2 * 64 +
                                                   ((G * 16) ^ ((row & 3) << 4)));
                yacc[c] = __builtin_amdgcn_mfma_f32_16x16x32_bf16(gf, pf, yacc[c], 0, 0, 0);
            }
            __builtin_amdgcn_s_setprio(0);
        }
        __builtin_amdgcn_s_barrier();   // all waves done reading buf[cur] before overwrite
    }

    lreg += __shfl_xor(lreg, 16);
    lreg += __shfl_xor(lreg, 32);

    const int sb = b * NSPLIT + s;
    if (lane < 16) lbuf[(size_t)sb * NN + qbase + lq] = lreg;
    const size_t nrow = ((size_t)sb * NN + qbase + lq) * CI;
#pragma unroll
    for (int c = 0; c < 8; ++c) {
        unsigned short pkk[4];
#pragma unroll
        for (int r = 0; r < 4; ++r) pkk[r] = f2bfbits(yacc[c][r]);
        *(uint2*)&yp[nrow + c * 16 + G * 4] = *(uint2*)pkk;
    }
}

// ---------------------------------------------------------------------------
// K3: output conv, fused combine (W . sum_s yp_s, then *inv_l + bias),
// bf16 MFMA split-W + BN partial sums.  [R8 structure, NSPLIT=4]
// grid (128 nt of 64 n, 2 cot, 2 b), 256 thr
// ---------------------------------------------------------------------------
__global__ __launch_bounds__(256, 2) void k_outconv(
    const unsigned short* __restrict__ yp, const float* __restrict__ lbuf,
    const unsigned short* __restrict__ woh, const unsigned short* __restrict__ wol,
    const float* __restrict__ obias, float* __restrict__ y2,
    float* __restrict__ psum, float* __restrict__ psq)
{
    const int nt_ = blockIdx.x, cot = blockIdx.y, b = blockIdx.z;
    const int nb = nt_ * 64;
    const int tid = threadIdx.x, wave = tid >> 6, lane = tid & 63;
    const int lq = lane & 15, G = lane >> 4;
    const int corow = cot * 128 + wave * 32;

    float inv[4];
#pragma unroll
    for (int nt = 0; nt < 4; ++nt) {
        const int n = nb + nt * 16 + lq;
        float l = 0.f;
#pragma unroll
        for (int s = 0; s < NSPLIT; ++s) l += lbuf[(size_t)(b * NSPLIT + s) * NN + n];
        inv[nt] = 1.f / l;
    }

    f32x4 acc[2][4];
#pragma unroll
    for (int ot = 0; ot < 2; ++ot)
#pragma unroll
        for (int nt = 0; nt < 4; ++nt) acc[ot][nt] = (f32x4){0.f, 0.f, 0.f, 0.f};

#pragma unroll
    for (int kc = 0; kc < 4; ++kc) {
        bf16x8 wh[2], wl[2];
#pragma unroll
        for (int ot = 0; ot < 2; ++ot) {
            const size_t wr = (size_t)(corow + ot * 16 + lq) * CI + kc * 32 + G * 8;
            wh[ot] = *(const bf16x8*)(woh + wr);
            wl[ot] = *(const bf16x8*)(wol + wr);
        }
#pragma unroll
        for (int s = 0; s < NSPLIT; ++s) {
            const unsigned short* xrow = yp + ((size_t)(b * NSPLIT + s) * NN + nb) * CI;
            bf16x8 xf[4];
#pragma unroll
            for (int nt = 0; nt < 4; ++nt)
                xf[nt] = *(const bf16x8*)(xrow + (size_t)(nt * 16 + lq) * CI + kc * 32 + G * 8);
#pragma unroll
            for (int ot = 0; ot < 2; ++ot)
#pragma unroll
                for (int nt = 0; nt < 4; ++nt) {
                    acc[ot][nt] = __builtin_amdgcn_mfma_f32_16x16x32_bf16(wh[ot], xf[nt], acc[ot][nt], 0, 0, 0);
                    acc[ot][nt] = __builtin_amdgcn_mfma_f32_16x16x32_bf16(wl[ot], xf[nt], acc[ot][nt], 0, 0, 0);
                }
        }
    }

#pragma unroll
    for (int ot = 0; ot < 2; ++ot) {
        const float4 bv = *(const float4*)&obias[corow + ot * 16 + G * 4];
#pragma unroll
        for (int nt = 0; nt < 4; ++nt) {
            acc[ot][nt][0] = acc[ot][nt][0] * inv[nt] + bv.x;
            acc[ot][nt][1] = acc[ot][nt][1] * inv[nt] + bv.y;
            acc[ot][nt][2] = acc[ot][nt][2] * inv[nt] + bv.z;
            acc[ot][nt][3] = acc[ot][nt][3] * inv[nt] + bv.w;
        }
    }

#pragma unroll
    for (int ot = 0; ot < 2; ++ot)
#pragma unroll
        for (int r = 0; r < 4; ++r) {
            const int co = corow + ot * 16 + G * 4 + r;
            float* dst = &y2[((size_t)b * CC + co) * NN + nb + lq];
#pragma unroll
            for (int nt = 0; nt < 4; ++nt) dst[nt * 16] = acc[ot][nt][r];
        }

#pragma unroll
    for (int ot = 0; ot < 2; ++ot)
#pragma unroll
        for (int r = 0; r < 4; ++r) {
            float sv = 0.f, q = 0.f;
#pragma unroll
            for (int nt = 0; nt < 4; ++nt) {
                const float v = acc[ot][nt][r];
                sv += v; q += v * v;
            }
#pragma unroll
            for (int d = 1; d < 16; d <<= 1) { sv += __shfl_xor(sv, d); q += __shfl_xor(q, d); }
            if (lq == 0) {
                const int co = corow + ot * 16 + G * 4 + r;
                psum[co * 256 + b * 128 + nt_] = sv;
                psq [co * 256 + b * 128 + nt_] = q;
            }
        }
}

// K4: reduce partials -> mean, inv_std
__global__ void k_red(const float* __restrict__ psum, const float* __restrict__ psq,
                      float* __restrict__ stats)
{
    const int co = threadIdx.x;
    float s = 0.f, q = 0.f;
    for (int i = 0; i < 256; ++i) { s += psum[co * 256 + i]; q += psq[co * 256 + i]; }
    const float mean = s * (1.f / 16384.f);
    const float var = q * (1.f / 16384.f) - mean * mean;
    stats[co] = mean;
    stats[256 + co] = rsqrtf(var + 1e-5f);
}

// K5: out = x + bn(y2) ; y2 lives in d_out, in-place
__global__ __launch_bounds__(256) void k_bn(
    const float* __restrict__ x, const float* __restrict__ bw,
    const float* __restrict__ bb, const float* __restrict__ stats,
    float* __restrict__ out)
{
    const int i4 = blockIdx.x * 256 + threadIdx.x;
    const int c = (i4 >> 11) & 255;
    const float a = stats[256 + c] * bw[c];
    const float bias2 = bb[c] - stats[c] * a;
    const float4 v = ((const float4*)out)[i4];
    const float4 xv = ((const float4*)x)[i4];
    float4 r;
    r.x = xv.x + v.x * a + bias2;
    r.y = xv.y + v.y * a + bias2;
    r.z = xv.z + v.z * a + bias2;
    r.w = xv.w + v.w * a + bias2;
    ((float4*)out)[i4] = r;
}

extern "C" void kernel_launch(void* const* d_in, const int* in_sizes, int n_in,
                              void* d_out, int out_size, void* d_ws, size_t ws_size,
                              hipStream_t stream) {
    const float* x       = (const float*)d_in[0];
    const float* g_w     = (const float*)d_in[1];
    const float* g_b     = (const float*)d_in[2];
    const float* theta_w = (const float*)d_in[3];
    const float* theta_b = (const float*)d_in[4];
    const float* phi_w   = (const float*)d_in[5];
    const float* phi_b   = (const float*)d_in[6];
    const float* out_w   = (const float*)d_in[7];
    const float* out_b   = (const float*)d_in[8];
    const float* bn_w    = (const float*)d_in[9];
    const float* bn_b    = (const float*)d_in[10];

    char* ws = (char*)d_ws;
    unsigned short* xT      = (unsigned short*)(ws + OFF_XT);
    unsigned short* wqh     = (unsigned short*)(ws + OFF_WQH);
    unsigned short* wql     = (unsigned short*)(ws + OFF_WQL);
    unsigned short* woh     = (unsigned short*)(ws + OFF_WOH);
    unsigned short* wol     = (unsigned short*)(ws + OFF_WOL);
    unsigned short* theta16 = (unsigned short*)(ws + OFF_THETA16);
    unsigned short* phi16   = (unsigned short*)(ws + OFF_PHI16);
    unsigned short* g16     = (unsigned short*)(ws + OFF_G16);
    unsigned short* yp      = (unsigned short*)(ws + OFF_YP);
    float* lbuf  = (float*)(ws + OFF_LBUF);
    float* psum  = (float*)(ws + OFF_PSUM);
    float* psq   = (float*)(ws + OFF_PSQ);
    float* stats = (float*)(ws + OFF_STAT);
    float* out   = (float*)d_out;

    k_xtprep<<<dim3(128, 4, 2), 256, 0, stream>>>(x, theta_w, phi_w, g_w, out_w,
                                                  xT, wqh, wql, woh, wol);
    k_qkvm<<<dim3(128, 3, 2), 256, 0, stream>>>(xT, wqh, wql, theta_b, phi_b, g_b,
                                                theta16, phi16, g16);
    k_attn<<<dim3(64, NSPLIT, 2), 512, 0, stream>>>(theta16, phi16, g16, yp, lbuf);
    k_outconv<<<dim3(128, 2, 2), 256, 0, stream>>>(yp, lbuf, woh, wol, out_b, out, psum, psq);
    k_red<<<1, 256, 0, stream>>>(psum, psq, stats);
    k_bn<<<4096, 256, 0, stream>>>(x, bn_w, bn_b, stats, out);
}

// Round 15
// 117.216 us; speedup vs baseline: 1.0004x; 1.0004x over previous
//
#include <hip/hip_runtime.h>
#include <math.h>

#define CC 256
#define CI 128
#define NN 8192
#define MM 2048
#define NSPLIT 4
#define KSPAN 512
#define KT 64
#define NCH 8
#define SUBC 20.0f

typedef __attribute__((ext_vector_type(8))) short bf16x8;
typedef __attribute__((ext_vector_type(4))) float f32x4;

// ws byte offsets
#define OFF_XT      0u
#define OFF_WQH     8388608u
#define OFF_WQL     8585216u
#define OFF_WOH     8781824u
#define OFF_WOL     8847360u
#define OFF_THETA16 8912896u
#define OFF_PHI16   13107200u
#define OFF_G16     14155776u
#define OFF_YP      15204352u
#define OFF_LBUF    48758784u
#define OFF_PSUM    49020928u
#define OFF_PSQ     49283072u
#define OFF_STAT    49545216u

static __device__ __forceinline__ unsigned short f2bfbits(float x) {
    unsigned u = __builtin_bit_cast(unsigned, x);
    u = u + 0x7fffu + ((u >> 16) & 1u);
    return (unsigned short)(u >> 16);
}
static __device__ __forceinline__ float bf2f(unsigned short h) {
    return __builtin_bit_cast(float, ((unsigned)h) << 16);
}
static __device__ __forceinline__ void gll16(const void* g, void* l) {
    __builtin_amdgcn_global_load_lds(
        (const __attribute__((address_space(1))) unsigned int*)g,
        (__attribute__((address_space(3))) unsigned int*)l, 16, 0, 0);
}

// ---------------------------------------------------------------------------
// K0: x fp32 [b][c][n] -> xT bf16 [b][n][c]  (+ fused weight hi/lo prep)
// grid (128, 4, 2), 256 thr   [R8, proven]
// ---------------------------------------------------------------------------
__global__ __launch_bounds__(256) void k_xtprep(
    const float* __restrict__ x,
    const float* __restrict__ tw, const float* __restrict__ pw,
    const float* __restrict__ gw, const float* __restrict__ ow,
    unsigned short* __restrict__ xT,
    unsigned short* __restrict__ wqh, unsigned short* __restrict__ wql,
    unsigned short* __restrict__ woh, unsigned short* __restrict__ wol)
{
    __shared__ float Xl[64 * 68];
    const int nb = blockIdx.x * 64, cb = blockIdx.y * 64, b = blockIdx.z;
    const int t = threadIdx.x;

    {
        const int fid = (((blockIdx.z * 4 + blockIdx.y) * 128 + blockIdx.x) * 256) + t;
        if (fid < 98304) {
            const float v = (fid < 32768) ? tw[fid] : (fid < 65536) ? pw[fid - 32768] : gw[fid - 65536];
            const unsigned short h = f2bfbits(v);
            wqh[fid] = h;
            wql[fid] = f2bfbits(v - bf2f(h));
        } else if (fid < 131072) {
            const int j = fid - 98304;
            const float v = ow[j];
            const unsigned short h = f2bfbits(v);
            woh[j] = h;
            wol[j] = f2bfbits(v - bf2f(h));
        }
    }

    const float* xb = x + ((size_t)b * CC + cb) * NN + nb;
    {
        const int cl = t >> 4, n4 = (t & 15) * 4;
#pragma unroll
        for (int i = 0; i < 4; ++i)
            *(float4*)&Xl[(cl + i * 16) * 68 + n4] =
                *(const float4*)&xb[(size_t)(cl + i * 16) * NN + n4];
    }
    __syncthreads();
    const int n = t >> 2, c0 = (t & 3) * 16;
    unsigned short v[16];
#pragma unroll
    for (int j = 0; j < 16; ++j) v[j] = f2bfbits(Xl[(c0 + j) * 68 + n]);
    unsigned short* dst = xT + ((size_t)b * NN + nb + n) * CC + cb + c0;
    *(uint4*)dst = *(uint4*)&v[0];
    *(uint4*)(dst + 8) = *(uint4*)&v[8];
}

// ---------------------------------------------------------------------------
// K1: theta/phi/g via bf16 MFMA, split-W  [R8, proven]
// grid (128, 3, 2), 256 thr
// ---------------------------------------------------------------------------
__global__ __launch_bounds__(256) void k_qkvm(
    const unsigned short* __restrict__ xT,
    const unsigned short* __restrict__ wqh, const unsigned short* __restrict__ wql,
    const float* __restrict__ tb, const float* __restrict__ pb, const float* __restrict__ gb,
    unsigned short* __restrict__ thetaT, unsigned short* __restrict__ phiT,
    unsigned short* __restrict__ gT)
{
    __shared__ unsigned short park[64 * 136];
    const int nt_ = blockIdx.x, sel = blockIdx.y, b = blockIdx.z;
    const int nb = nt_ * 64;
    const int tid = threadIdx.x, wave = tid >> 6, lane = tid & 63;
    const int lq = lane & 15, G = lane >> 4;
    const int obase = wave * 32;
    const int orow = sel * 128 + obase;
    const float* bias = (sel == 0) ? tb : (sel == 1) ? pb : gb;

    f32x4 acc[2][4];
#pragma unroll
    for (int ot = 0; ot < 2; ++ot)
#pragma unroll
        for (int nt = 0; nt < 4; ++nt) acc[ot][nt] = (f32x4){0.f, 0.f, 0.f, 0.f};

    const unsigned short* xrow = xT + ((size_t)b * NN + nb) * CC;
#pragma unroll
    for (int kc = 0; kc < 8; ++kc) {
        bf16x8 wh[2], wl[2], xf[4];
#pragma unroll
        for (int ot = 0; ot < 2; ++ot) {
            const size_t wr = (size_t)(orow + ot * 16 + lq) * CC + kc * 32 + G * 8;
            wh[ot] = *(const bf16x8*)(wqh + wr);
            wl[ot] = *(const bf16x8*)(wql + wr);
        }
#pragma unroll
        for (int nt = 0; nt < 4; ++nt)
            xf[nt] = *(const bf16x8*)(xrow + (size_t)(nt * 16 + lq) * CC + kc * 32 + G * 8);
#pragma unroll
        for (int ot = 0; ot < 2; ++ot)
#pragma unroll
            for (int nt = 0; nt < 4; ++nt) {
                acc[ot][nt] = __builtin_amdgcn_mfma_f32_16x16x32_bf16(wh[ot], xf[nt], acc[ot][nt], 0, 0, 0);
                acc[ot][nt] = __builtin_amdgcn_mfma_f32_16x16x32_bf16(wl[ot], xf[nt], acc[ot][nt], 0, 0, 0);
            }
    }
#pragma unroll
    for (int ot = 0; ot < 2; ++ot) {
        const float4 bv = *(const float4*)&bias[obase + ot * 16 + G * 4];
#pragma unroll
        for (int nt = 0; nt < 4; ++nt) {
            acc[ot][nt][0] += bv.x; acc[ot][nt][1] += bv.y;
            acc[ot][nt][2] += bv.z; acc[ot][nt][3] += bv.w;
        }
    }

    if (sel == 0) {
#pragma unroll
        for (int ot = 0; ot < 2; ++ot)
#pragma unroll
            for (int nt = 0; nt < 4; ++nt) {
                unsigned short pk[4];
#pragma unroll
                for (int r = 0; r < 4; ++r) pk[r] = f2bfbits(acc[ot][nt][r]);
                const int n = nb + nt * 16 + lq;
                const int ci = obase + ot * 16 + G * 4;
                *(uint2*)&thetaT[((size_t)b * NN + n) * CI + ci] = *(uint2*)pk;
            }
    } else {
#pragma unroll
        for (int ot = 0; ot < 2; ++ot)
#pragma unroll
            for (int nt = 0; nt < 4; ++nt) {
                unsigned short pk[4];
#pragma unroll
                for (int r = 0; r < 4; ++r) pk[r] = f2bfbits(acc[ot][nt][r]);
                const int n = nt * 16 + lq;
                const int o = obase + ot * 16 + G * 4;
                *(uint2*)&park[n * 136 + o] = *(uint2*)pk;
            }
        __syncthreads();
        const int tfrm = nb >> 10, h0 = (nb >> 5) & 31;
        const int mb = tfrm * 256 + (h0 >> 1) * 16;
        if (sel == 1) {
            for (int idx = tid; idx < 2048; idx += 256) {
                const int o = idx & 127, m = idx >> 7;
                const float v = fmaxf(
                    fmaxf(bf2f(park[(2 * m) * 136 + o]), bf2f(park[(2 * m + 1) * 136 + o])),
                    fmaxf(bf2f(park[(32 + 2 * m) * 136 + o]), bf2f(park[(33 + 2 * m) * 136 + o])));
                phiT[((size_t)b * MM + mb + m) * CI + o] = f2bfbits(v);
            }
        } else {
            for (int idx = tid; idx < 2048; idx += 256) {
                const int o = idx >> 4, m = idx & 15;
                const float v = fmaxf(
                    fmaxf(bf2f(park[(2 * m) * 136 + o]), bf2f(park[(2 * m + 1) * 136 + o])),
                    fmaxf(bf2f(park[(32 + 2 * m) * 136 + o]), bf2f(park[(33 + 2 * m) * 136 + o])));
                gT[((size_t)b * CI + o) * MM + mb + m] = f2bfbits(v);
            }
        }
    }
}

// ---------------------------------------------------------------------------
// K2: flash attention, static-max, counted vmcnt  [R12 kernel, NSPLIT=4]
// grid (64 qblk, 4 s, 2 b) = 512 blocks (2/CU, 4 waves/SIMD), 512 thr,
// 16 q/wave, KT=64 dbuf, NCH=8.
// ---------------------------------------------------------------------------
__global__ __launch_bounds__(512, 4) void k_attn(
    const unsigned short* __restrict__ thetaT,
    const unsigned short* __restrict__ phiT,
    const unsigned short* __restrict__ gT,
    unsigned short* __restrict__ yp,
    float* __restrict__ lbuf)
{
    __shared__ __align__(16) char smem[73728];  // 2 x (phi 16K + g 16K) + P 8K
    const int tid  = threadIdx.x;
    const int wave = tid >> 6;
    const int lane = tid & 63;
    const int lq = lane & 15, G = lane >> 4;
    const int qblk = blockIdx.x, s = blockIdx.y, b = blockIdx.z;
    const int qbase = qblk * 128 + wave * 16;
    const int koff0 = s * KSPAN;

    bf16x8 tf[4];
    {
        const size_t row = (size_t)b * NN + qbase + lq;
#pragma unroll
        for (int D = 0; D < 4; ++D)
            tf[D] = *(const bf16x8*)(thetaT + row * CI + D * 32 + G * 8);
    }

    const char* phiSrc = (const char*)(phiT + (size_t)b * MM * CI);
    const char* gSrc   = (const char*)(gT   + (size_t)b * CI * MM);
    int pk[2], pco[2];
#pragma unroll
    for (int i = 0; i < 2; ++i) {
        pk[i]  = wave * 8 + i * 4 + (lane >> 4);
        pco[i] = ((lane & 15) ^ (pk[i] & 7)) << 4;
    }
    const int gr0 = wave * 16 + (lane >> 3);
    const int u_  = lane & 7;
    const int gu  = (u_ & 4) | ((u_ & 3) ^ (gr0 & 3));

    auto STAGE = [&](int buf, int koff) {
        char* pl = smem + buf * 32768 + wave * 2048;
        char* gl = smem + buf * 32768 + 16384 + wave * 2048;
#pragma unroll
        for (int i = 0; i < 2; ++i) {
            gll16(phiSrc + (size_t)(koff + pk[i]) * 256 + pco[i], pl + i * 1024);
            gll16(gSrc + (size_t)(gr0 + i * 8) * 4096 + (size_t)koff * 2 + gu * 16, gl + i * 1024);
        }
    };

    f32x4 yacc[8];
#pragma unroll
    for (int c = 0; c < 8; ++c) yacc[c] = (f32x4){0.f, 0.f, 0.f, 0.f};
    float lreg = 0.f;

    STAGE(0, koff0);

    char* pP = smem + 65536 + wave * 1024;
    const int swq = (lq & 3) << 4;
    const int swk = (lq & 7) << 4;

    for (int ch = 0; ch < NCH; ++ch) {
        const int cur = ch & 1;
        if (ch < NCH - 1) {
            STAGE(cur ^ 1, koff0 + (ch + 1) * KT);
            // 8 outstanding: wait for the 4 oldest (buf[cur]); 4 newest stay in flight
            asm volatile("s_waitcnt vmcnt(4)" ::: "memory");
        } else {
            asm volatile("s_waitcnt vmcnt(0)" ::: "memory");
        }
        __builtin_amdgcn_s_barrier();   // all waves' buf[cur] loads landed

        const char* pbuf = smem + cur * 32768;
        const char* gbuf = smem + cur * 32768 + 16384;

#pragma unroll
        for (int t2 = 0; t2 < 2; ++t2) {
            f32x4 sacc[2];
            sacc[0] = (f32x4){0.f, 0.f, 0.f, 0.f};
            sacc[1] = (f32x4){0.f, 0.f, 0.f, 0.f};
            __builtin_amdgcn_s_setprio(1);
#pragma unroll
            for (int D = 0; D < 4; ++D) {
                const int co = (((D * 4 + G) << 4) ^ swk);
                const bf16x8 a0 = *(const bf16x8*)(pbuf + (t2 * 32 + lq) * 256 + co);
                const bf16x8 a1 = *(const bf16x8*)(pbuf + (t2 * 32 + 16 + lq) * 256 + co);
                sacc[0] = __builtin_amdgcn_mfma_f32_16x16x32_bf16(a0, tf[D], sacc[0], 0, 0, 0);
                sacc[1] = __builtin_amdgcn_mfma_f32_16x16x32_bf16(a1, tf[D], sacc[1], 0, 0, 0);
            }
            __builtin_amdgcn_s_setprio(0);

            float p[8];
#pragma unroll
            for (int ks = 0; ks < 2; ++ks)
#pragma unroll
                for (int r = 0; r < 4; ++r) {
                    const float e = __expf(sacc[ks][r] - SUBC);
                    p[ks * 4 + r] = e;
                    lreg += e;
                }
#pragma unroll
            for (int ks = 0; ks < 2; ++ks)
#pragma unroll
                for (int r2 = 0; r2 < 2; ++r2) {
                    const unsigned w = (unsigned)f2bfbits(p[ks * 4 + r2 * 2]) |
                                       ((unsigned)f2bfbits(p[ks * 4 + r2 * 2 + 1]) << 16);
                    const int byt = (ks * 32 + G * 8 + r2 * 4) ^ swq;
                    *(unsigned*)(pP + lq * 64 + byt) = w;
                }

            const bf16x8 pf = *(const bf16x8*)(pP + lq * 64 + ((G * 16) ^ swq));
            __builtin_amdgcn_s_setprio(1);
#pragma unroll
            for (int c = 0; c < 8; ++c) {
                const int row = c * 16 + lq;
                const bf16x8 gf = *(const bf16x8*)(gbuf + row * 128 + t2 * 64 +
                                                   ((G * 16) ^ ((row & 3) << 4)));
                yacc[c] = __builtin_amdgcn_mfma_f32_16x16x32_bf16(gf, pf, yacc[c], 0, 0, 0);
            }
            __builtin_amdgcn_s_setprio(0);
        }
        __builtin_amdgcn_s_barrier();   // all waves done reading buf[cur] before overwrite
    }

    lreg += __shfl_xor(lreg, 16);
    lreg += __shfl_xor(lreg, 32);

    const int sb = b * NSPLIT + s;
    if (lane < 16) lbuf[(size_t)sb * NN + qbase + lq] = lreg;
    const size_t nrow = ((size_t)sb * NN + qbase + lq) * CI;
#pragma unroll
    for (int c = 0; c < 8; ++c) {
        unsigned short pkk[4];
#pragma unroll
        for (int r = 0; r < 4; ++r) pkk[r] = f2bfbits(yacc[c][r]);
        *(uint2*)&yp[nrow + c * 16 + G * 4] = *(uint2*)pkk;
    }
}

// ---------------------------------------------------------------------------
// K3: output conv, fused combine (W . sum_s yp_s, then *inv_l + bias),
// bf16 MFMA split-W + BN partial sums.  [R8 structure, NSPLIT=4]
// grid (128 nt of 64 n, 2 cot, 2 b), 256 thr
// ---------------------------------------------------------------------------
__global__ __launch_bounds__(256, 2) void k_outconv(
    const unsigned short* __restrict__ yp, const float* __restrict__ lbuf,
    const unsigned short* __restrict__ woh, const unsigned short* __restrict__ wol,
    const float* __restrict__ obias, float* __restrict__ y2,
    float* __restrict__ psum, float* __restrict__ psq)
{
    const int nt_ = blockIdx.x, cot = blockIdx.y, b = blockIdx.z;
    const int nb = nt_ * 64;
    const int tid = threadIdx.x, wave = tid >> 6, lane = tid & 63;
    const int lq = lane & 15, G = lane >> 4;
    const int corow = cot * 128 + wave * 32;

    float inv[4];
#pragma unroll
    for (int nt = 0; nt < 4; ++nt) {
        const int n = nb + nt * 16 + lq;
        float l = 0.f;
#pragma unroll
        for (int s = 0; s < NSPLIT; ++s) l += lbuf[(size_t)(b * NSPLIT + s) * NN + n];
        inv[nt] = 1.f / l;
    }

    f32x4 acc[2][4];
#pragma unroll
    for (int ot = 0; ot < 2; ++ot)
#pragma unroll
        for (int nt = 0; nt < 4; ++nt) acc[ot][nt] = (f32x4){0.f, 0.f, 0.f, 0.f};

#pragma unroll
    for (int kc = 0; kc < 4; ++kc) {
        bf16x8 wh[2], wl[2];
#pragma unroll
        for (int ot = 0; ot < 2; ++ot) {
            const size_t wr = (size_t)(corow + ot * 16 + lq) * CI + kc * 32 + G * 8;
            wh[ot] = *(const bf16x8*)(woh + wr);
            wl[ot] = *(const bf16x8*)(wol + wr);
        }
#pragma unroll
        for (int s = 0; s < NSPLIT; ++s) {
            const unsigned short* xrow = yp + ((size_t)(b * NSPLIT + s) * NN + nb) * CI;
            bf16x8 xf[4];
#pragma unroll
            for (int nt = 0; nt < 4; ++nt)
                xf[nt] = *(const bf16x8*)(xrow + (size_t)(nt * 16 + lq) * CI + kc * 32 + G * 8);
#pragma unroll
            for (int ot = 0; ot < 2; ++ot)
#pragma unroll
                for (int nt = 0; nt < 4; ++nt) {
                    acc[ot][nt] = __builtin_amdgcn_mfma_f32_16x16x32_bf16(wh[ot], xf[nt], acc[ot][nt], 0, 0, 0);
                    acc[ot][nt] = __builtin_amdgcn_mfma_f32_16x16x32_bf16(wl[ot], xf[nt], acc[ot][nt], 0, 0, 0);
                }
        }
    }

#pragma unroll
    for (int ot = 0; ot < 2; ++ot) {
        const float4 bv = *(const float4*)&obias[corow + ot * 16 + G * 4];
#pragma unroll
        for (int nt = 0; nt < 4; ++nt) {
            acc[ot][nt][0] = acc[ot][nt][0] * inv[nt] + bv.x;
            acc[ot][nt][1] = acc[ot][nt][1] * inv[nt] + bv.y;
            acc[ot][nt][2] = acc[ot][nt][2] * inv[nt] + bv.z;
            acc[ot][nt][3] = acc[ot][nt][3] * inv[nt] + bv.w;
        }
    }

#pragma unroll
    for (int ot = 0; ot < 2; ++ot)
#pragma unroll
        for (int r = 0; r < 4; ++r) {
            const int co = corow + ot * 16 + G * 4 + r;
            float* dst = &y2[((size_t)b * CC + co) * NN + nb + lq];
#pragma unroll
            for (int nt = 0; nt < 4; ++nt) dst[nt * 16] = acc[ot][nt][r];
        }

#pragma unroll
    for (int ot = 0; ot < 2; ++ot)
#pragma unroll
        for (int r = 0; r < 4; ++r) {
            float sv = 0.f, q = 0.f;
#pragma unroll
            for (int nt = 0; nt < 4; ++nt) {
                const float v = acc[ot][nt][r];
                sv += v; q += v * v;
            }
#pragma unroll
            for (int d = 1; d < 16; d <<= 1) { sv += __shfl_xor(sv, d); q += __shfl_xor(q, d); }
            if (lq == 0) {
                const int co = corow + ot * 16 + G * 4 + r;
                psum[co * 256 + b * 128 + nt_] = sv;
                psq [co * 256 + b * 128 + nt_] = q;
            }
        }
}

// K4: reduce partials -> mean, inv_std
__global__ void k_red(const float* __restrict__ psum, const float* __restrict__ psq,
                      float* __restrict__ stats)
{
    const int co = threadIdx.x;
    float s = 0.f, q = 0.f;
    for (int i = 0; i < 256; ++i) { s += psum[co * 256 + i]; q += psq[co * 256 + i]; }
    const float mean = s * (1.f / 16384.f);
    const float var = q * (1.f / 16384.f) - mean * mean;
    stats[co] = mean;
    stats[256 + co] = rsqrtf(var + 1e-5f);
}

// K5: out = x + bn(y2) ; y2 lives in d_out, in-place
__global__ __launch_bounds__(256) void k_bn(
    const float* __restrict__ x, const float* __restrict__ bw,
    const float* __restrict__ bb, const float* __restrict__ stats,
    float* __restrict__ out)
{
    const int i4 = blockIdx.x * 256 + threadIdx.x;
    const int c = (i4 >> 11) & 255;
    const float a = stats[256 + c] * bw[c];
    const float bias2 = bb[c] - stats[c] * a;
    const float4 v = ((const float4*)out)[i4];
    const float4 xv = ((const float4*)x)[i4];
    float4 r;
    r.x = xv.x + v.x * a + bias2;
    r.y = xv.y + v.y * a + bias2;
    r.z = xv.z + v.z * a + bias2;
    r.w = xv.w + v.w * a + bias2;
    ((float4*)out)[i4] = r;
}

extern "C" void kernel_launch(void* const* d_in, const int* in_sizes, int n_in,
                              void* d_out, int out_size, void* d_ws, size_t ws_size,
                              hipStream_t stream) {
    const float* x       = (const float*)d_in[0];
    const float* g_w     = (const float*)d_in[1];
    const float* g_b     = (const float*)d_in[2];
    const float* theta_w = (const float*)d_in[3];
    const float* theta_b = (const float*)d_in[4];
    const float* phi_w   = (const float*)d_in[5];
    const float* phi_b   = (const float*)d_in[6];
    const float* out_w   = (const float*)d_in[7];
    const float* out_b   = (const float*)d_in[8];
    const float* bn_w    = (const float*)d_in[9];
    const float* bn_b    = (const float*)d_in[10];

    char* ws = (char*)d_ws;
    unsigned short* xT      = (unsigned short*)(ws + OFF_XT);
    unsigned short* wqh     = (unsigned short*)(ws + OFF_WQH);
    unsigned short* wql     = (unsigned short*)(ws + OFF_WQL);
    unsigned short* woh     = (unsigned short*)(ws + OFF_WOH);
    unsigned short* wol     = (unsigned short*)(ws + OFF_WOL);
    unsigned short* theta16 = (unsigned short*)(ws + OFF_THETA16);
    unsigned short* phi16   = (unsigned short*)(ws + OFF_PHI16);
    unsigned short* g16     = (unsigned short*)(ws + OFF_G16);
    unsigned short* yp      = (unsigned short*)(ws + OFF_YP);
    float* lbuf  = (float*)(ws + OFF_LBUF);
    float* psum  = (float*)(ws + OFF_PSUM);
    float* psq   = (float*)(ws + OFF_PSQ);
    float* stats = (float*)(ws + OFF_STAT);
    float* out   = (float*)d_out;

    k_xtprep<<<dim3(128, 4, 2), 256, 0, stream>>>(x, theta_w, phi_w, g_w, out_w,
                                                  xT, wqh, wql, woh, wol);
    k_qkvm<<<dim3(128, 3, 2), 256, 0, stream>>>(xT, wqh, wql, theta_b, phi_b, g_b,
                                                theta16, phi16, g16);
    k_attn<<<dim3(64, NSPLIT, 2), 512, 0, stream>>>(theta16, phi16, g16, yp, lbuf);
    k_outconv<<<dim3(128, 2, 2), 256, 0, stream>>>(yp, lbuf, woh, wol, out_b, out, psum, psq);
    k_red<<<1, 256, 0, stream>>>(psum, psq, stats);
    k_bn<<<4096, 256, 0, stream>>>(x, bn_w, bn_b, stats, out);
}

// Round 16
// 109.007 us; speedup vs baseline: 1.0757x; 1.0753x over previous
//
#include <hip/hip_runtime.h>
#include <math.h>

#define CC 256
#define CI 128
#define NN 8192
#define MM 2048
#define NSPLIT 2
#define KSPAN 1024
#define KT 64
#define NCH 16
#define SUBC 20.0f

typedef __attribute__((ext_vector_type(8))) short bf16x8;
typedef __attribute__((ext_vector_type(4))) float f32x4;

// ws byte offsets
#define OFF_XT      0u
#define OFF_WQH     8388608u
#define OFF_WQL     8585216u
#define OFF_WOH     8781824u
#define OFF_WOL     8847360u
#define OFF_THETA16 8912896u
#define OFF_PHI16   13107200u
#define OFF_G16     14155776u
#define OFF_YP      15204352u
#define OFF_LBUF    23592960u
#define OFF_PSUM    23724032u
#define OFF_PSQ     23986176u
#define OFF_STAT    24248320u
#define OFF_Y2      25165824u

static __device__ __forceinline__ unsigned short f2bfbits(float x) {
    unsigned u = __builtin_bit_cast(unsigned, x);
    u = u + 0x7fffu + ((u >> 16) & 1u);
    return (unsigned short)(u >> 16);
}
static __device__ __forceinline__ float bf2f(unsigned short h) {
    return __builtin_bit_cast(float, ((unsigned)h) << 16);
}
static __device__ __forceinline__ void gll16(const void* g, void* l) {
    __builtin_amdgcn_global_load_lds(
        (const __attribute__((address_space(1))) unsigned int*)g,
        (__attribute__((address_space(3))) unsigned int*)l, 16, 0, 0);
}

// ---------------------------------------------------------------------------
// K0: x fp32 [b][c][n] -> xT bf16 [b][n][c]  (+ fused weight hi/lo prep)
// grid (128, 4, 2), 256 thr   [R8, proven]
// ---------------------------------------------------------------------------
__global__ __launch_bounds__(256) void k_xtprep(
    const float* __restrict__ x,
    const float* __restrict__ tw, const float* __restrict__ pw,
    const float* __restrict__ gw, const float* __restrict__ ow,
    unsigned short* __restrict__ xT,
    unsigned short* __restrict__ wqh, unsigned short* __restrict__ wql,
    unsigned short* __restrict__ woh, unsigned short* __restrict__ wol)
{
    __shared__ float Xl[64 * 68];
    const int nb = blockIdx.x * 64, cb = blockIdx.y * 64, b = blockIdx.z;
    const int t = threadIdx.x;

    {
        const int fid = (((blockIdx.z * 4 + blockIdx.y) * 128 + blockIdx.x) * 256) + t;
        if (fid < 98304) {
            const float v = (fid < 32768) ? tw[fid] : (fid < 65536) ? pw[fid - 32768] : gw[fid - 65536];
            const unsigned short h = f2bfbits(v);
            wqh[fid] = h;
            wql[fid] = f2bfbits(v - bf2f(h));
        } else if (fid < 131072) {
            const int j = fid - 98304;
            const float v = ow[j];
            const unsigned short h = f2bfbits(v);
            woh[j] = h;
            wol[j] = f2bfbits(v - bf2f(h));
        }
    }

    const float* xb = x + ((size_t)b * CC + cb) * NN + nb;
    {
        const int cl = t >> 4, n4 = (t & 15) * 4;
#pragma unroll
        for (int i = 0; i < 4; ++i)
            *(float4*)&Xl[(cl + i * 16) * 68 + n4] =
                *(const float4*)&xb[(size_t)(cl + i * 16) * NN + n4];
    }
    __syncthreads();
    const int n = t >> 2, c0 = (t & 3) * 16;
    unsigned short v[16];
#pragma unroll
    for (int j = 0; j < 16; ++j) v[j] = f2bfbits(Xl[(c0 + j) * 68 + n]);
    unsigned short* dst = xT + ((size_t)b * NN + nb + n) * CC + cb + c0;
    *(uint4*)dst = *(uint4*)&v[0];
    *(uint4*)(dst + 8) = *(uint4*)&v[8];
}

// ---------------------------------------------------------------------------
// K1: theta/phi/g via bf16 MFMA, split-W  [R8, proven]
// grid (128, 3, 2), 256 thr
// ---------------------------------------------------------------------------
__global__ __launch_bounds__(256) void k_qkvm(
    const unsigned short* __restrict__ xT,
    const unsigned short* __restrict__ wqh, const unsigned short* __restrict__ wql,
    const float* __restrict__ tb, const float* __restrict__ pb, const float* __restrict__ gb,
    unsigned short* __restrict__ thetaT, unsigned short* __restrict__ phiT,
    unsigned short* __restrict__ gT)
{
    __shared__ unsigned short park[64 * 136];
    const int nt_ = blockIdx.x, sel = blockIdx.y, b = blockIdx.z;
    const int nb = nt_ * 64;
    const int tid = threadIdx.x, wave = tid >> 6, lane = tid & 63;
    const int lq = lane & 15, G = lane >> 4;
    const int obase = wave * 32;
    const int orow = sel * 128 + obase;
    const float* bias = (sel == 0) ? tb : (sel == 1) ? pb : gb;

    f32x4 acc[2][4];
#pragma unroll
    for (int ot = 0; ot < 2; ++ot)
#pragma unroll
        for (int nt = 0; nt < 4; ++nt) acc[ot][nt] = (f32x4){0.f, 0.f, 0.f, 0.f};

    const unsigned short* xrow = xT + ((size_t)b * NN + nb) * CC;
#pragma unroll
    for (int kc = 0; kc < 8; ++kc) {
        bf16x8 wh[2], wl[2], xf[4];
#pragma unroll
        for (int ot = 0; ot < 2; ++ot) {
            const size_t wr = (size_t)(orow + ot * 16 + lq) * CC + kc * 32 + G * 8;
            wh[ot] = *(const bf16x8*)(wqh + wr);
            wl[ot] = *(const bf16x8*)(wql + wr);
        }
#pragma unroll
        for (int nt = 0; nt < 4; ++nt)
            xf[nt] = *(const bf16x8*)(xrow + (size_t)(nt * 16 + lq) * CC + kc * 32 + G * 8);
#pragma unroll
        for (int ot = 0; ot < 2; ++ot)
#pragma unroll
            for (int nt = 0; nt < 4; ++nt) {
                acc[ot][nt] = __builtin_amdgcn_mfma_f32_16x16x32_bf16(wh[ot], xf[nt], acc[ot][nt], 0, 0, 0);
                acc[ot][nt] = __builtin_amdgcn_mfma_f32_16x16x32_bf16(wl[ot], xf[nt], acc[ot][nt], 0, 0, 0);
            }
    }
#pragma unroll
    for (int ot = 0; ot < 2; ++ot) {
        const float4 bv = *(const float4*)&bias[obase + ot * 16 + G * 4];
#pragma unroll
        for (int nt = 0; nt < 4; ++nt) {
            acc[ot][nt][0] += bv.x; acc[ot][nt][1] += bv.y;
            acc[ot][nt][2] += bv.z; acc[ot][nt][3] += bv.w;
        }
    }

    if (sel == 0) {
#pragma unroll
        for (int ot = 0; ot < 2; ++ot)
#pragma unroll
            for (int nt = 0; nt < 4; ++nt) {
                unsigned short pk[4];
#pragma unroll
                for (int r = 0; r < 4; ++r) pk[r] = f2bfbits(acc[ot][nt][r]);
                const int n = nb + nt * 16 + lq;
                const int ci = obase + ot * 16 + G * 4;
                *(uint2*)&thetaT[((size_t)b * NN + n) * CI + ci] = *(uint2*)pk;
            }
    } else {
#pragma unroll
        for (int ot = 0; ot < 2; ++ot)
#pragma unroll
            for (int nt = 0; nt < 4; ++nt) {
                unsigned short pk[4];
#pragma unroll
                for (int r = 0; r < 4; ++r) pk[r] = f2bfbits(acc[ot][nt][r]);
                const int n = nt * 16 + lq;
                const int o = obase + ot * 16 + G * 4;
                *(uint2*)&park[n * 136 + o] = *(uint2*)pk;
            }
        __syncthreads();
        const int tfrm = nb >> 10, h0 = (nb >> 5) & 31;
        const int mb = tfrm * 256 + (h0 >> 1) * 16;
        if (sel == 1) {
            for (int idx = tid; idx < 2048; idx += 256) {
                const int o = idx & 127, m = idx >> 7;
                const float v = fmaxf(
                    fmaxf(bf2f(park[(2 * m) * 136 + o]), bf2f(park[(2 * m + 1) * 136 + o])),
                    fmaxf(bf2f(park[(32 + 2 * m) * 136 + o]), bf2f(park[(33 + 2 * m) * 136 + o])));
                phiT[((size_t)b * MM + mb + m) * CI + o] = f2bfbits(v);
            }
        } else {
            for (int idx = tid; idx < 2048; idx += 256) {
                const int o = idx >> 4, m = idx & 15;
                const float v = fmaxf(
                    fmaxf(bf2f(park[(2 * m) * 136 + o]), bf2f(park[(2 * m + 1) * 136 + o])),
                    fmaxf(bf2f(park[(32 + 2 * m) * 136 + o]), bf2f(park[(33 + 2 * m) * 136 + o])));
                gT[((size_t)b * CI + o) * MM + mb + m] = f2bfbits(v);
            }
        }
    }
}

// ---------------------------------------------------------------------------
// K2: flash attention, static-max  [R8, proven]
// grid (64 qblk, 2 s, 2 b), 512 thr = 8 waves, 16 q/wave, KT=64 dbuf.
// ---------------------------------------------------------------------------
__global__ __launch_bounds__(512, 4) void k_attn(
    const unsigned short* __restrict__ thetaT,
    const unsigned short* __restrict__ phiT,
    const unsigned short* __restrict__ gT,
    unsigned short* __restrict__ yp,
    float* __restrict__ lbuf)
{
    __shared__ __align__(16) char smem[73728];  // 2 x (phi 16K + g 16K) + P 8K
    const int tid  = threadIdx.x;
    const int wave = tid >> 6;
    const int lane = tid & 63;
    const int lq = lane & 15, G = lane >> 4;
    const int qblk = blockIdx.x, s = blockIdx.y, b = blockIdx.z;
    const int qbase = qblk * 128 + wave * 16;
    const int koff0 = s * KSPAN;

    bf16x8 tf[4];
    {
        const size_t row = (size_t)b * NN + qbase + lq;
#pragma unroll
        for (int D = 0; D < 4; ++D)
            tf[D] = *(const bf16x8*)(thetaT + row * CI + D * 32 + G * 8);
    }

    const char* phiSrc = (const char*)(phiT + (size_t)b * MM * CI);
    const char* gSrc   = (const char*)(gT   + (size_t)b * CI * MM);
    int pk[2], pco[2];
#pragma unroll
    for (int i = 0; i < 2; ++i) {
        pk[i]  = wave * 8 + i * 4 + (lane >> 4);
        pco[i] = ((lane & 15) ^ (pk[i] & 7)) << 4;
    }
    const int gr0 = wave * 16 + (lane >> 3);
    const int u_  = lane & 7;
    const int gu  = (u_ & 4) | ((u_ & 3) ^ (gr0 & 3));

    auto STAGE = [&](int buf, int koff) {
        char* pl = smem + buf * 32768 + wave * 2048;
        char* gl = smem + buf * 32768 + 16384 + wave * 2048;
#pragma unroll
        for (int i = 0; i < 2; ++i) {
            gll16(phiSrc + (size_t)(koff + pk[i]) * 256 + pco[i], pl + i * 1024);
            gll16(gSrc + (size_t)(gr0 + i * 8) * 4096 + (size_t)koff * 2 + gu * 16, gl + i * 1024);
        }
    };

    f32x4 yacc[8];
#pragma unroll
    for (int c = 0; c < 8; ++c) yacc[c] = (f32x4){0.f, 0.f, 0.f, 0.f};
    float lreg = 0.f;

    STAGE(0, koff0);
    __syncthreads();

    char* pP = smem + 65536 + wave * 1024;
    const int swq = (lq & 3) << 4;
    const int swk = (lq & 7) << 4;

    for (int ch = 0; ch < NCH; ++ch) {
        const int cur = ch & 1;
        if (ch < NCH - 1) STAGE(cur ^ 1, koff0 + (ch + 1) * KT);
        const char* pbuf = smem + cur * 32768;
        const char* gbuf = smem + cur * 32768 + 16384;

#pragma unroll
        for (int t2 = 0; t2 < 2; ++t2) {
            f32x4 sacc[2];
            sacc[0] = (f32x4){0.f, 0.f, 0.f, 0.f};
            sacc[1] = (f32x4){0.f, 0.f, 0.f, 0.f};
            __builtin_amdgcn_s_setprio(1);
#pragma unroll
            for (int D = 0; D < 4; ++D) {
                const int co = (((D * 4 + G) << 4) ^ swk);
                const bf16x8 a0 = *(const bf16x8*)(pbuf + (t2 * 32 + lq) * 256 + co);
                const bf16x8 a1 = *(const bf16x8*)(pbuf + (t2 * 32 + 16 + lq) * 256 + co);
                sacc[0] = __builtin_amdgcn_mfma_f32_16x16x32_bf16(a0, tf[D], sacc[0], 0, 0, 0);
                sacc[1] = __builtin_amdgcn_mfma_f32_16x16x32_bf16(a1, tf[D], sacc[1], 0, 0, 0);
            }
            __builtin_amdgcn_s_setprio(0);

            float p[8];
#pragma unroll
            for (int ks = 0; ks < 2; ++ks)
#pragma unroll
                for (int r = 0; r < 4; ++r) {
                    const float e = __expf(sacc[ks][r] - SUBC);
                    p[ks * 4 + r] = e;
                    lreg += e;
                }
#pragma unroll
            for (int ks = 0; ks < 2; ++ks)
#pragma unroll
                for (int r2 = 0; r2 < 2; ++r2) {
                    const unsigned w = (unsigned)f2bfbits(p[ks * 4 + r2 * 2]) |
                                       ((unsigned)f2bfbits(p[ks * 4 + r2 * 2 + 1]) << 16);
                    const int byt = (ks * 32 + G * 8 + r2 * 4) ^ swq;
                    *(unsigned*)(pP + lq * 64 + byt) = w;
                }

            const bf16x8 pf = *(const bf16x8*)(pP + lq * 64 + ((G * 16) ^ swq));
            __builtin_amdgcn_s_setprio(1);
#pragma unroll
            for (int c = 0; c < 8; ++c) {
                const int row = c * 16 + lq;
                const bf16x8 gf = *(const bf16x8*)(gbuf + row * 128 + t2 * 64 +
                                                   ((G * 16) ^ ((row & 3) << 4)));
                yacc[c] = __builtin_amdgcn_mfma_f32_16x16x32_bf16(gf, pf, yacc[c], 0, 0, 0);
            }
            __builtin_amdgcn_s_setprio(0);
        }
        __syncthreads();
    }

    lreg += __shfl_xor(lreg, 16);
    lreg += __shfl_xor(lreg, 32);

    const int sb = b * NSPLIT + s;
    if (lane < 16) lbuf[(size_t)sb * NN + qbase + lq] = lreg;
    const size_t nrow = ((size_t)sb * NN + qbase + lq) * CI;
#pragma unroll
    for (int c = 0; c < 8; ++c) {
        unsigned short pkk[4];
#pragma unroll
        for (int r = 0; r < 4; ++r) pkk[r] = f2bfbits(yacc[c][r]);
        *(uint2*)&yp[nrow + c * 16 + G * 4] = *(uint2*)pkk;
    }
}

// ---------------------------------------------------------------------------
// K3: output conv, fused combine, bf16 MFMA split-W + BN partial sums.
// [R8, proven; y2 now stored bf16 in ws]
// grid (128 nt of 64 n, 2 cot, 2 b), 256 thr
// ---------------------------------------------------------------------------
__global__ __launch_bounds__(256, 2) void k_outconv(
    const unsigned short* __restrict__ yp, const float* __restrict__ lbuf,
    const unsigned short* __restrict__ woh, const unsigned short* __restrict__ wol,
    const float* __restrict__ obias, unsigned short* __restrict__ y2,
    float* __restrict__ psum, float* __restrict__ psq)
{
    const int nt_ = blockIdx.x, cot = blockIdx.y, b = blockIdx.z;
    const int nb = nt_ * 64;
    const int tid = threadIdx.x, wave = tid >> 6, lane = tid & 63;
    const int lq = lane & 15, G = lane >> 4;
    const int corow = cot * 128 + wave * 32;

    float inv[4];
#pragma unroll
    for (int nt = 0; nt < 4; ++nt) {
        const int n = nb + nt * 16 + lq;
        float l = 0.f;
#pragma unroll
        for (int s = 0; s < NSPLIT; ++s) l += lbuf[(size_t)(b * NSPLIT + s) * NN + n];
        inv[nt] = 1.f / l;
    }

    f32x4 acc[2][4];
#pragma unroll
    for (int ot = 0; ot < 2; ++ot)
#pragma unroll
        for (int nt = 0; nt < 4; ++nt) acc[ot][nt] = (f32x4){0.f, 0.f, 0.f, 0.f};

#pragma unroll
    for (int kc = 0; kc < 4; ++kc) {
        bf16x8 wh[2], wl[2];
#pragma unroll
        for (int ot = 0; ot < 2; ++ot) {
            const size_t wr = (size_t)(corow + ot * 16 + lq) * CI + kc * 32 + G * 8;
            wh[ot] = *(const bf16x8*)(woh + wr);
            wl[ot] = *(const bf16x8*)(wol + wr);
        }
#pragma unroll
        for (int s = 0; s < NSPLIT; ++s) {
            const unsigned short* xrow = yp + ((size_t)(b * NSPLIT + s) * NN + nb) * CI;
            bf16x8 xf[4];
#pragma unroll
            for (int nt = 0; nt < 4; ++nt)
                xf[nt] = *(const bf16x8*)(xrow + (size_t)(nt * 16 + lq) * CI + kc * 32 + G * 8);
#pragma unroll
            for (int ot = 0; ot < 2; ++ot)
#pragma unroll
                for (int nt = 0; nt < 4; ++nt) {
                    acc[ot][nt] = __builtin_amdgcn_mfma_f32_16x16x32_bf16(wh[ot], xf[nt], acc[ot][nt], 0, 0, 0);
                    acc[ot][nt] = __builtin_amdgcn_mfma_f32_16x16x32_bf16(wl[ot], xf[nt], acc[ot][nt], 0, 0, 0);
                }
        }
    }

#pragma unroll
    for (int ot = 0; ot < 2; ++ot) {
        const float4 bv = *(const float4*)&obias[corow + ot * 16 + G * 4];
#pragma unroll
        for (int nt = 0; nt < 4; ++nt) {
            acc[ot][nt][0] = acc[ot][nt][0] * inv[nt] + bv.x;
            acc[ot][nt][1] = acc[ot][nt][1] * inv[nt] + bv.y;
            acc[ot][nt][2] = acc[ot][nt][2] * inv[nt] + bv.z;
            acc[ot][nt][3] = acc[ot][nt][3] * inv[nt] + bv.w;
        }
    }

    // y2 [b][co][n] bf16 (stats below use fp32 acc, unaffected by rounding)
#pragma unroll
    for (int ot = 0; ot < 2; ++ot)
#pragma unroll
        for (int r = 0; r < 4; ++r) {
            const int co = corow + ot * 16 + G * 4 + r;
            unsigned short* dst = &y2[((size_t)b * CC + co) * NN + nb + lq];
#pragma unroll
            for (int nt = 0; nt < 4; ++nt) dst[nt * 16] = f2bfbits(acc[ot][nt][r]);
        }

#pragma unroll
    for (int ot = 0; ot < 2; ++ot)
#pragma unroll
        for (int r = 0; r < 4; ++r) {
            float sv = 0.f, q = 0.f;
#pragma unroll
            for (int nt = 0; nt < 4; ++nt) {
                const float v = acc[ot][nt][r];
                sv += v; q += v * v;
            }
#pragma unroll
            for (int d = 1; d < 16; d <<= 1) { sv += __shfl_xor(sv, d); q += __shfl_xor(q, d); }
            if (lq == 0) {
                const int co = corow + ot * 16 + G * 4 + r;
                psum[co * 256 + b * 128 + nt_] = sv;
                psq [co * 256 + b * 128 + nt_] = q;
            }
        }
}

// K4: reduce partials -> mean, inv_std
__global__ void k_red(const float* __restrict__ psum, const float* __restrict__ psq,
                      float* __restrict__ stats)
{
    const int co = threadIdx.x;
    float s = 0.f, q = 0.f;
    for (int i = 0; i < 256; ++i) { s += psum[co * 256 + i]; q += psq[co * 256 + i]; }
    const float mean = s * (1.f / 16384.f);
    const float var = q * (1.f / 16384.f) - mean * mean;
    stats[co] = mean;
    stats[256 + co] = rsqrtf(var + 1e-5f);
}

// K5: out = x + bn(y2) ; y2 bf16 from ws, out fp32 to d_out
__global__ __launch_bounds__(256) void k_bn(
    const float* __restrict__ x, const unsigned short* __restrict__ y2,
    const float* __restrict__ bw, const float* __restrict__ bb,
    const float* __restrict__ stats, float* __restrict__ out)
{
    const int i4 = blockIdx.x * 256 + threadIdx.x;   // 1048576 groups of 4 floats
    const int c = (i4 >> 11) & 255;
    const float a = stats[256 + c] * bw[c];
    const float bias2 = bb[c] - stats[c] * a;
    const uint2 v2 = ((const uint2*)y2)[i4];
    const float4 xv = ((const float4*)x)[i4];
    float4 r;
    r.x = xv.x + bf2f((unsigned short)(v2.x & 0xffff)) * a + bias2;
    r.y = xv.y + bf2f((unsigned short)(v2.x >> 16))    * a + bias2;
    r.z = xv.z + bf2f((unsigned short)(v2.y & 0xffff)) * a + bias2;
    r.w = xv.w + bf2f((unsigned short)(v2.y >> 16))    * a + bias2;
    ((float4*)out)[i4] = r;
}

extern "C" void kernel_launch(void* const* d_in, const int* in_sizes, int n_in,
                              void* d_out, int out_size, void* d_ws, size_t ws_size,
                              hipStream_t stream) {
    const float* x       = (const float*)d_in[0];
    const float* g_w     = (const float*)d_in[1];
    const float* g_b     = (const float*)d_in[2];
    const float* theta_w = (const float*)d_in[3];
    const float* theta_b = (const float*)d_in[4];
    const float* phi_w   = (const float*)d_in[5];
    const float* phi_b   = (const float*)d_in[6];
    const float* out_w   = (const float*)d_in[7];
    const float* out_b   = (const float*)d_in[8];
    const float* bn_w    = (const float*)d_in[9];
    const float* bn_b    = (const float*)d_in[10];

    char* ws = (char*)d_ws;
    unsigned short* xT      = (unsigned short*)(ws + OFF_XT);
    unsigned short* wqh     = (unsigned short*)(ws + OFF_WQH);
    unsigned short* wql     = (unsigned short*)(ws + OFF_WQL);
    unsigned short* woh     = (unsigned short*)(ws + OFF_WOH);
    unsigned short* wol     = (unsigned short*)(ws + OFF_WOL);
    unsigned short* theta16 = (unsigned short*)(ws + OFF_THETA16);
    unsigned short* phi16   = (unsigned short*)(ws + OFF_PHI16);
    unsigned short* g16     = (unsigned short*)(ws + OFF_G16);
    unsigned short* yp      = (unsigned short*)(ws + OFF_YP);
    unsigned short* y2      = (unsigned short*)(ws + OFF_Y2);
    float* lbuf  = (float*)(ws + OFF_LBUF);
    float* psum  = (float*)(ws + OFF_PSUM);
    float* psq   = (float*)(ws + OFF_PSQ);
    float* stats = (float*)(ws + OFF_STAT);
    float* out   = (float*)d_out;

    k_xtprep<<<dim3(128, 4, 2), 256, 0, stream>>>(x, theta_w, phi_w, g_w, out_w,
                                                  xT, wqh, wql, woh, wol);
    k_qkvm<<<dim3(128, 3, 2), 256, 0, stream>>>(xT, wqh, wql, theta_b, phi_b, g_b,
                                                theta16, phi16, g16);
    k_attn<<<dim3(64, NSPLIT, 2), 512, 0, stream>>>(theta16, phi16, g16, yp, lbuf);
    k_outconv<<<dim3(128, 2, 2), 256, 0, stream>>>(yp, lbuf, woh, wol, out_b, y2, psum, psq);
    k_red<<<1, 256, 0, stream>>>(psum, psq, stats);
    k_bn<<<4096, 256, 0, stream>>>(x, y2, bn_w, bn_b, stats, out);
}

// Round 17
// 108.498 us; speedup vs baseline: 1.0807x; 1.0047x over previous
//
#include <hip/hip_runtime.h>
#include <math.h>

#define CC 256
#define CI 128
#define NN 8192
#define MM 2048
#define NSPLIT 2
#define KSPAN 1024
#define KT 64
#define NCH 16
#define SUBC 20.0f

typedef __attribute__((ext_vector_type(8))) short bf16x8;
typedef __attribute__((ext_vector_type(4))) float f32x4;

// ws byte offsets
#define OFF_XT      0u
#define OFF_WQH     8388608u
#define OFF_WQL     8585216u
#define OFF_WOH     8781824u
#define OFF_WOL     8847360u
#define OFF_THETA16 8912896u
#define OFF_PHI16   13107200u
#define OFF_G16     14155776u
#define OFF_YP      15204352u
#define OFF_LBUF    23592960u
#define OFF_PSUM    23724032u
#define OFF_PSQ     23986176u
#define OFF_STAT    24248320u
#define OFF_Y2      25165824u

static __device__ __forceinline__ unsigned short f2bfbits(float x) {
    unsigned u = __builtin_bit_cast(unsigned, x);
    u = u + 0x7fffu + ((u >> 16) & 1u);
    return (unsigned short)(u >> 16);
}
static __device__ __forceinline__ float bf2f(unsigned short h) {
    return __builtin_bit_cast(float, ((unsigned)h) << 16);
}
static __device__ __forceinline__ void gll16(const void* g, void* l) {
    __builtin_amdgcn_global_load_lds(
        (const __attribute__((address_space(1))) unsigned int*)g,
        (__attribute__((address_space(3))) unsigned int*)l, 16, 0, 0);
}

// ---------------------------------------------------------------------------
// K0: x fp32 [b][c][n] -> xT bf16 [b][n][c]  (+ fused weight hi/lo prep)
// grid (128, 4, 2), 256 thr   [R8/R16, proven]
// ---------------------------------------------------------------------------
__global__ __launch_bounds__(256) void k_xtprep(
    const float* __restrict__ x,
    const float* __restrict__ tw, const float* __restrict__ pw,
    const float* __restrict__ gw, const float* __restrict__ ow,
    unsigned short* __restrict__ xT,
    unsigned short* __restrict__ wqh, unsigned short* __restrict__ wql,
    unsigned short* __restrict__ woh, unsigned short* __restrict__ wol)
{
    __shared__ float Xl[64 * 68];
    const int nb = blockIdx.x * 64, cb = blockIdx.y * 64, b = blockIdx.z;
    const int t = threadIdx.x;

    {
        const int fid = (((blockIdx.z * 4 + blockIdx.y) * 128 + blockIdx.x) * 256) + t;
        if (fid < 98304) {
            const float v = (fid < 32768) ? tw[fid] : (fid < 65536) ? pw[fid - 32768] : gw[fid - 65536];
            const unsigned short h = f2bfbits(v);
            wqh[fid] = h;
            wql[fid] = f2bfbits(v - bf2f(h));
        } else if (fid < 131072) {
            const int j = fid - 98304;
            const float v = ow[j];
            const unsigned short h = f2bfbits(v);
            woh[j] = h;
            wol[j] = f2bfbits(v - bf2f(h));
        }
    }

    const float* xb = x + ((size_t)b * CC + cb) * NN + nb;
    {
        const int cl = t >> 4, n4 = (t & 15) * 4;
#pragma unroll
        for (int i = 0; i < 4; ++i)
            *(float4*)&Xl[(cl + i * 16) * 68 + n4] =
                *(const float4*)&xb[(size_t)(cl + i * 16) * NN + n4];
    }
    __syncthreads();
    const int n = t >> 2, c0 = (t & 3) * 16;
    unsigned short v[16];
#pragma unroll
    for (int j = 0; j < 16; ++j) v[j] = f2bfbits(Xl[(c0 + j) * 68 + n]);
    unsigned short* dst = xT + ((size_t)b * NN + nb + n) * CC + cb + c0;
    *(uint4*)dst = *(uint4*)&v[0];
    *(uint4*)(dst + 8) = *(uint4*)&v[8];
}

// ---------------------------------------------------------------------------
// K1: theta/phi/g via bf16 MFMA, split-W  [R8/R16, proven]
// grid (128, 3, 2), 256 thr
// ---------------------------------------------------------------------------
__global__ __launch_bounds__(256) void k_qkvm(
    const unsigned short* __restrict__ xT,
    const unsigned short* __restrict__ wqh, const unsigned short* __restrict__ wql,
    const float* __restrict__ tb, const float* __restrict__ pb, const float* __restrict__ gb,
    unsigned short* __restrict__ thetaT, unsigned short* __restrict__ phiT,
    unsigned short* __restrict__ gT)
{
    __shared__ unsigned short park[64 * 136];
    const int nt_ = blockIdx.x, sel = blockIdx.y, b = blockIdx.z;
    const int nb = nt_ * 64;
    const int tid = threadIdx.x, wave = tid >> 6, lane = tid & 63;
    const int lq = lane & 15, G = lane >> 4;
    const int obase = wave * 32;
    const int orow = sel * 128 + obase;
    const float* bias = (sel == 0) ? tb : (sel == 1) ? pb : gb;

    f32x4 acc[2][4];
#pragma unroll
    for (int ot = 0; ot < 2; ++ot)
#pragma unroll
        for (int nt = 0; nt < 4; ++nt) acc[ot][nt] = (f32x4){0.f, 0.f, 0.f, 0.f};

    const unsigned short* xrow = xT + ((size_t)b * NN + nb) * CC;
#pragma unroll
    for (int kc = 0; kc < 8; ++kc) {
        bf16x8 wh[2], wl[2], xf[4];
#pragma unroll
        for (int ot = 0; ot < 2; ++ot) {
            const size_t wr = (size_t)(orow + ot * 16 + lq) * CC + kc * 32 + G * 8;
            wh[ot] = *(const bf16x8*)(wqh + wr);
            wl[ot] = *(const bf16x8*)(wql + wr);
        }
#pragma unroll
        for (int nt = 0; nt < 4; ++nt)
            xf[nt] = *(const bf16x8*)(xrow + (size_t)(nt * 16 + lq) * CC + kc * 32 + G * 8);
#pragma unroll
        for (int ot = 0; ot < 2; ++ot)
#pragma unroll
            for (int nt = 0; nt < 4; ++nt) {
                acc[ot][nt] = __builtin_amdgcn_mfma_f32_16x16x32_bf16(wh[ot], xf[nt], acc[ot][nt], 0, 0, 0);
                acc[ot][nt] = __builtin_amdgcn_mfma_f32_16x16x32_bf16(wl[ot], xf[nt], acc[ot][nt], 0, 0, 0);
            }
    }
#pragma unroll
    for (int ot = 0; ot < 2; ++ot) {
        const float4 bv = *(const float4*)&bias[obase + ot * 16 + G * 4];
#pragma unroll
        for (int nt = 0; nt < 4; ++nt) {
            acc[ot][nt][0] += bv.x; acc[ot][nt][1] += bv.y;
            acc[ot][nt][2] += bv.z; acc[ot][nt][3] += bv.w;
        }
    }

    if (sel == 0) {
#pragma unroll
        for (int ot = 0; ot < 2; ++ot)
#pragma unroll
            for (int nt = 0; nt < 4; ++nt) {
                unsigned short pk[4];
#pragma unroll
                for (int r = 0; r < 4; ++r) pk[r] = f2bfbits(acc[ot][nt][r]);
                const int n = nb + nt * 16 + lq;
                const int ci = obase + ot * 16 + G * 4;
                *(uint2*)&thetaT[((size_t)b * NN + n) * CI + ci] = *(uint2*)pk;
            }
    } else {
#pragma unroll
        for (int ot = 0; ot < 2; ++ot)
#pragma unroll
            for (int nt = 0; nt < 4; ++nt) {
                unsigned short pk[4];
#pragma unroll
                for (int r = 0; r < 4; ++r) pk[r] = f2bfbits(acc[ot][nt][r]);
                const int n = nt * 16 + lq;
                const int o = obase + ot * 16 + G * 4;
                *(uint2*)&park[n * 136 + o] = *(uint2*)pk;
            }
        __syncthreads();
        const int tfrm = nb >> 10, h0 = (nb >> 5) & 31;
        const int mb = tfrm * 256 + (h0 >> 1) * 16;
        if (sel == 1) {
            for (int idx = tid; idx < 2048; idx += 256) {
                const int o = idx & 127, m = idx >> 7;
                const float v = fmaxf(
                    fmaxf(bf2f(park[(2 * m) * 136 + o]), bf2f(park[(2 * m + 1) * 136 + o])),
                    fmaxf(bf2f(park[(32 + 2 * m) * 136 + o]), bf2f(park[(33 + 2 * m) * 136 + o])));
                phiT[((size_t)b * MM + mb + m) * CI + o] = f2bfbits(v);
            }
        } else {
            for (int idx = tid; idx < 2048; idx += 256) {
                const int o = idx >> 4, m = idx & 15;
                const float v = fmaxf(
                    fmaxf(bf2f(park[(2 * m) * 136 + o]), bf2f(park[(2 * m + 1) * 136 + o])),
                    fmaxf(bf2f(park[(32 + 2 * m) * 136 + o]), bf2f(park[(33 + 2 * m) * 136 + o])));
                gT[((size_t)b * CI + o) * MM + mb + m] = f2bfbits(v);
            }
        }
    }
}

// ---------------------------------------------------------------------------
// K2: flash attention, static-max  [R16 + per-t2 P double-buffer]
// grid (64 qblk, 2 s, 2 b), 512 thr = 8 waves, 16 q/wave, KT=64 dbuf.
// P buffer is wave-private; double-buffering across t2 removes the
// write-after-read serialization so t2=1 QK/exp can overlap t2=0 PV.
// ---------------------------------------------------------------------------
__global__ __launch_bounds__(512, 4) void k_attn(
    const unsigned short* __restrict__ thetaT,
    const unsigned short* __restrict__ phiT,
    const unsigned short* __restrict__ gT,
    unsigned short* __restrict__ yp,
    float* __restrict__ lbuf)
{
    __shared__ __align__(16) char smem[81920];  // 2 x (phi 16K + g 16K) + P 2x8K
    const int tid  = threadIdx.x;
    const int wave = tid >> 6;
    const int lane = tid & 63;
    const int lq = lane & 15, G = lane >> 4;
    const int qblk = blockIdx.x, s = blockIdx.y, b = blockIdx.z;
    const int qbase = qblk * 128 + wave * 16;
    const int koff0 = s * KSPAN;

    bf16x8 tf[4];
    {
        const size_t row = (size_t)b * NN + qbase + lq;
#pragma unroll
        for (int D = 0; D < 4; ++D)
            tf[D] = *(const bf16x8*)(thetaT + row * CI + D * 32 + G * 8);
    }

    const char* phiSrc = (const char*)(phiT + (size_t)b * MM * CI);
    const char* gSrc   = (const char*)(gT   + (size_t)b * CI * MM);
    int pk[2], pco[2];
#pragma unroll
    for (int i = 0; i < 2; ++i) {
        pk[i]  = wave * 8 + i * 4 + (lane >> 4);
        pco[i] = ((lane & 15) ^ (pk[i] & 7)) << 4;
    }
    const int gr0 = wave * 16 + (lane >> 3);
    const int u_  = lane & 7;
    const int gu  = (u_ & 4) | ((u_ & 3) ^ (gr0 & 3));

    auto STAGE = [&](int buf, int koff) {
        char* pl = smem + buf * 32768 + wave * 2048;
        char* gl = smem + buf * 32768 + 16384 + wave * 2048;
#pragma unroll
        for (int i = 0; i < 2; ++i) {
            gll16(phiSrc + (size_t)(koff + pk[i]) * 256 + pco[i], pl + i * 1024);
            gll16(gSrc + (size_t)(gr0 + i * 8) * 4096 + (size_t)koff * 2 + gu * 16, gl + i * 1024);
        }
    };

    f32x4 yacc[8];
#pragma unroll
    for (int c = 0; c < 8; ++c) yacc[c] = (f32x4){0.f, 0.f, 0.f, 0.f};
    float lreg = 0.f;

    STAGE(0, koff0);
    __syncthreads();

    char* pPb[2] = { smem + 65536 + wave * 1024, smem + 73728 + wave * 1024 };
    const int swq = (lq & 3) << 4;
    const int swk = (lq & 7) << 4;

    for (int ch = 0; ch < NCH; ++ch) {
        const int cur = ch & 1;
        if (ch < NCH - 1) STAGE(cur ^ 1, koff0 + (ch + 1) * KT);
        const char* pbuf = smem + cur * 32768;
        const char* gbuf = smem + cur * 32768 + 16384;

#pragma unroll
        for (int t2 = 0; t2 < 2; ++t2) {
            char* pP = pPb[t2];
            f32x4 sacc[2];
            sacc[0] = (f32x4){0.f, 0.f, 0.f, 0.f};
            sacc[1] = (f32x4){0.f, 0.f, 0.f, 0.f};
            __builtin_amdgcn_s_setprio(1);
#pragma unroll
            for (int D = 0; D < 4; ++D) {
                const int co = (((D * 4 + G) << 4) ^ swk);
                const bf16x8 a0 = *(const bf16x8*)(pbuf + (t2 * 32 + lq) * 256 + co);
                const bf16x8 a1 = *(const bf16x8*)(pbuf + (t2 * 32 + 16 + lq) * 256 + co);
                sacc[0] = __builtin_amdgcn_mfma_f32_16x16x32_bf16(a0, tf[D], sacc[0], 0, 0, 0);
                sacc[1] = __builtin_amdgcn_mfma_f32_16x16x32_bf16(a1, tf[D], sacc[1], 0, 0, 0);
            }
            __builtin_amdgcn_s_setprio(0);

            float p[8];
#pragma unroll
            for (int ks = 0; ks < 2; ++ks)
#pragma unroll
                for (int r = 0; r < 4; ++r) {
                    const float e = __expf(sacc[ks][r] - SUBC);
                    p[ks * 4 + r] = e;
                    lreg += e;
                }
#pragma unroll
            for (int ks = 0; ks < 2; ++ks)
#pragma unroll
                for (int r2 = 0; r2 < 2; ++r2) {
                    const unsigned w = (unsigned)f2bfbits(p[ks * 4 + r2 * 2]) |
                                       ((unsigned)f2bfbits(p[ks * 4 + r2 * 2 + 1]) << 16);
                    const int byt = (ks * 32 + G * 8 + r2 * 4) ^ swq;
                    *(unsigned*)(pP + lq * 64 + byt) = w;
                }

            const bf16x8 pf = *(const bf16x8*)(pP + lq * 64 + ((G * 16) ^ swq));
            __builtin_amdgcn_s_setprio(1);
#pragma unroll
            for (int c = 0; c < 8; ++c) {
                const int row = c * 16 + lq;
                const bf16x8 gf = *(const bf16x8*)(gbuf + row * 128 + t2 * 64 +
                                                   ((G * 16) ^ ((row & 3) << 4)));
                yacc[c] = __builtin_amdgcn_mfma_f32_16x16x32_bf16(gf, pf, yacc[c], 0, 0, 0);
            }
            __builtin_amdgcn_s_setprio(0);
        }
        __syncthreads();
    }

    lreg += __shfl_xor(lreg, 16);
    lreg += __shfl_xor(lreg, 32);

    const int sb = b * NSPLIT + s;
    if (lane < 16) lbuf[(size_t)sb * NN + qbase + lq] = lreg;
    const size_t nrow = ((size_t)sb * NN + qbase + lq) * CI;
#pragma unroll
    for (int c = 0; c < 8; ++c) {
        unsigned short pkk[4];
#pragma unroll
        for (int r = 0; r < 4; ++r) pkk[r] = f2bfbits(yacc[c][r]);
        *(uint2*)&yp[nrow + c * 16 + G * 4] = *(uint2*)pkk;
    }
}

// ---------------------------------------------------------------------------
// K3: output conv, fused combine, bf16 MFMA split-W + BN partial sums.
// [R16, proven; y2 bf16 in ws]
// grid (128 nt of 64 n, 2 cot, 2 b), 256 thr
// ---------------------------------------------------------------------------
__global__ __launch_bounds__(256, 2) void k_outconv(
    const unsigned short* __restrict__ yp, const float* __restrict__ lbuf,
    const unsigned short* __restrict__ woh, const unsigned short* __restrict__ wol,
    const float* __restrict__ obias, unsigned short* __restrict__ y2,
    float* __restrict__ psum, float* __restrict__ psq)
{
    const int nt_ = blockIdx.x, cot = blockIdx.y, b = blockIdx.z;
    const int nb = nt_ * 64;
    const int tid = threadIdx.x, wave = tid >> 6, lane = tid & 63;
    const int lq = lane & 15, G = lane >> 4;
    const int corow = cot * 128 + wave * 32;

    float inv[4];
#pragma unroll
    for (int nt = 0; nt < 4; ++nt) {
        const int n = nb + nt * 16 + lq;
        float l = 0.f;
#pragma unroll
        for (int s = 0; s < NSPLIT; ++s) l += lbuf[(size_t)(b * NSPLIT + s) * NN + n];
        inv[nt] = 1.f / l;
    }

    f32x4 acc[2][4];
#pragma unroll
    for (int ot = 0; ot < 2; ++ot)
#pragma unroll
        for (int nt = 0; nt < 4; ++nt) acc[ot][nt] = (f32x4){0.f, 0.f, 0.f, 0.f};

#pragma unroll
    for (int kc = 0; kc < 4; ++kc) {
        bf16x8 wh[2], wl[2];
#pragma unroll
        for (int ot = 0; ot < 2; ++ot) {
            const size_t wr = (size_t)(corow + ot * 16 + lq) * CI + kc * 32 + G * 8;
            wh[ot] = *(const bf16x8*)(woh + wr);
            wl[ot] = *(const bf16x8*)(wol + wr);
        }
#pragma unroll
        for (int s = 0; s < NSPLIT; ++s) {
            const unsigned short* xrow = yp + ((size_t)(b * NSPLIT + s) * NN + nb) * CI;
            bf16x8 xf[4];
#pragma unroll
            for (int nt = 0; nt < 4; ++nt)
                xf[nt] = *(const bf16x8*)(xrow + (size_t)(nt * 16 + lq) * CI + kc * 32 + G * 8);
#pragma unroll
            for (int ot = 0; ot < 2; ++ot)
#pragma unroll
                for (int nt = 0; nt < 4; ++nt) {
                    acc[ot][nt] = __builtin_amdgcn_mfma_f32_16x16x32_bf16(wh[ot], xf[nt], acc[ot][nt], 0, 0, 0);
                    acc[ot][nt] = __builtin_amdgcn_mfma_f32_16x16x32_bf16(wl[ot], xf[nt], acc[ot][nt], 0, 0, 0);
                }
        }
    }

#pragma unroll
    for (int ot = 0; ot < 2; ++ot) {
        const float4 bv = *(const float4*)&obias[corow + ot * 16 + G * 4];
#pragma unroll
        for (int nt = 0; nt < 4; ++nt) {
            acc[ot][nt][0] = acc[ot][nt][0] * inv[nt] + bv.x;
            acc[ot][nt][1] = acc[ot][nt][1] * inv[nt] + bv.y;
            acc[ot][nt][2] = acc[ot][nt][2] * inv[nt] + bv.z;
            acc[ot][nt][3] = acc[ot][nt][3] * inv[nt] + bv.w;
        }
    }

    // y2 [b][co][n] bf16 (stats below use fp32 acc, unaffected by rounding)
#pragma unroll
    for (int ot = 0; ot < 2; ++ot)
#pragma unroll
        for (int r = 0; r < 4; ++r) {
            const int co = corow + ot * 16 + G * 4 + r;
            unsigned short* dst = &y2[((size_t)b * CC + co) * NN + nb + lq];
#pragma unroll
            for (int nt = 0; nt < 4; ++nt) dst[nt * 16] = f2bfbits(acc[ot][nt][r]);
        }

#pragma unroll
    for (int ot = 0; ot < 2; ++ot)
#pragma unroll
        for (int r = 0; r < 4; ++r) {
            float sv = 0.f, q = 0.f;
#pragma unroll
            for (int nt = 0; nt < 4; ++nt) {
                const float v = acc[ot][nt][r];
                sv += v; q += v * v;
            }
#pragma unroll
            for (int d = 1; d < 16; d <<= 1) { sv += __shfl_xor(sv, d); q += __shfl_xor(q, d); }
            if (lq == 0) {
                const int co = corow + ot * 16 + G * 4 + r;
                psum[co * 256 + b * 128 + nt_] = sv;
                psq [co * 256 + b * 128 + nt_] = q;
            }
        }
}

// K4: reduce partials -> mean, inv_std
__global__ void k_red(const float* __restrict__ psum, const float* __restrict__ psq,
                      float* __restrict__ stats)
{
    const int co = threadIdx.x;
    float s = 0.f, q = 0.f;
    for (int i = 0; i < 256; ++i) { s += psum[co * 256 + i]; q += psq[co * 256 + i]; }
    const float mean = s * (1.f / 16384.f);
    const float var = q * (1.f / 16384.f) - mean * mean;
    stats[co] = mean;
    stats[256 + co] = rsqrtf(var + 1e-5f);
}

// K5: out = x + bn(y2) ; y2 bf16 from ws, out fp32 to d_out
__global__ __launch_bounds__(256) void k_bn(
    const float* __restrict__ x, const unsigned short* __restrict__ y2,
    const float* __restrict__ bw, const float* __restrict__ bb,
    const float* __restrict__ stats, float* __restrict__ out)
{
    const int i4 = blockIdx.x * 256 + threadIdx.x;
    const int c = (i4 >> 11) & 255;
    const float a = stats[256 + c] * bw[c];
    const float bias2 = bb[c] - stats[c] * a;
    const uint2 v2 = ((const uint2*)y2)[i4];
    const float4 xv = ((const float4*)x)[i4];
    float4 r;
    r.x = xv.x + bf2f((unsigned short)(v2.x & 0xffff)) * a + bias2;
    r.y = xv.y + bf2f((unsigned short)(v2.x >> 16))    * a + bias2;
    r.z = xv.z + bf2f((unsigned short)(v2.y & 0xffff)) * a + bias2;
    r.w = xv.w + bf2f((unsigned short)(v2.y >> 16))    * a + bias2;
    ((float4*)out)[i4] = r;
}

extern "C" void kernel_launch(void* const* d_in, const int* in_sizes, int n_in,
                              void* d_out, int out_size, void* d_ws, size_t ws_size,
                              hipStream_t stream) {
    const float* x       = (const float*)d_in[0];
    const float* g_w     = (const float*)d_in[1];
    const float* g_b     = (const float*)d_in[2];
    const float* theta_w = (const float*)d_in[3];
    const float* theta_b = (const float*)d_in[4];
    const float* phi_w   = (const float*)d_in[5];
    const float* phi_b   = (const float*)d_in[6];
    const float* out_w   = (const float*)d_in[7];
    const float* out_b   = (const float*)d_in[8];
    const float* bn_w    = (const float*)d_in[9];
    const float* bn_b    = (const float*)d_in[10];

    char* ws = (char*)d_ws;
    unsigned short* xT      = (unsigned short*)(ws + OFF_XT);
    unsigned short* wqh     = (unsigned short*)(ws + OFF_WQH);
    unsigned short* wql     = (unsigned short*)(ws + OFF_WQL);
    unsigned short* woh     = (unsigned short*)(ws + OFF_WOH);
    unsigned short* wol     = (unsigned short*)(ws + OFF_WOL);
    unsigned short* theta16 = (unsigned short*)(ws + OFF_THETA16);
    unsigned short* phi16   = (unsigned short*)(ws + OFF_PHI16);
    unsigned short* g16     = (unsigned short*)(ws + OFF_G16);
    unsigned short* yp      = (unsigned short*)(ws + OFF_YP);
    unsigned short* y2      = (unsigned short*)(ws + OFF_Y2);
    float* lbuf  = (float*)(ws + OFF_LBUF);
    float* psum  = (float*)(ws + OFF_PSUM);
    float* psq   = (float*)(ws + OFF_PSQ);
    float* stats = (float*)(ws + OFF_STAT);
    float* out   = (float*)d_out;

    k_xtprep<<<dim3(128, 4, 2), 256, 0, stream>>>(x, theta_w, phi_w, g_w, out_w,
                                                  xT, wqh, wql, woh, wol);
    k_qkvm<<<dim3(128, 3, 2), 256, 0, stream>>>(xT, wqh, wql, theta_b, phi_b, g_b,
                                                theta16, phi16, g16);
    k_attn<<<dim3(64, NSPLIT, 2), 512, 0, stream>>>(theta16, phi16, g16, yp, lbuf);
    k_outconv<<<dim3(128, 2, 2), 256, 0, stream>>>(yp, lbuf, woh, wol, out_b, y2, psum, psq);
    k_red<<<1, 256, 0, stream>>>(psum, psq, stats);
    k_bn<<<4096, 256, 0, stream>>>(x, y2, bn_w, bn_b, stats, out);
}

// Round 18
// 100.548 us; speedup vs baseline: 1.1662x; 1.0791x over previous
//
#include <hip/hip_runtime.h>
#include <math.h>

#define CC 256
#define CI 128
#define NN 8192
#define MM 2048
#define NSPLIT 2
#define KSPAN 1024
#define KT 64
#define NCH 16
#define SUBC 20.0f

typedef __attribute__((ext_vector_type(8))) short bf16x8;
typedef __attribute__((ext_vector_type(4))) float f32x4;

// ws byte offsets
#define OFF_WQH     8388608u
#define OFF_WQL     8585216u
#define OFF_WOH     8781824u
#define OFF_WOL     8847360u
#define OFF_THETA16 8912896u
#define OFF_PHI16   13107200u
#define OFF_G16     14155776u
#define OFF_YP      15204352u
#define OFF_LBUF    23592960u
#define OFF_PSUM    23724032u
#define OFF_PSQ     23986176u
#define OFF_STAT    24248320u
#define OFF_Y2      25165824u

static __device__ __forceinline__ unsigned short f2bfbits(float x) {
    unsigned u = __builtin_bit_cast(unsigned, x);
    u = u + 0x7fffu + ((u >> 16) & 1u);
    return (unsigned short)(u >> 16);
}
static __device__ __forceinline__ float bf2f(unsigned short h) {
    return __builtin_bit_cast(float, ((unsigned)h) << 16);
}
static __device__ __forceinline__ void gll16(const void* g, void* l) {
    __builtin_amdgcn_global_load_lds(
        (const __attribute__((address_space(1))) unsigned int*)g,
        (__attribute__((address_space(3))) unsigned int*)l, 16, 0, 0);
}

// ---------------------------------------------------------------------------
// K0: weight hi/lo split only.  grid (256), 512 thr (131072 elems exactly)
// ---------------------------------------------------------------------------
__global__ __launch_bounds__(512) void k_prep(
    const float* __restrict__ tw, const float* __restrict__ pw,
    const float* __restrict__ gw, const float* __restrict__ ow,
    unsigned short* __restrict__ wqh, unsigned short* __restrict__ wql,
    unsigned short* __restrict__ woh, unsigned short* __restrict__ wol)
{
    const int i = blockIdx.x * 512 + threadIdx.x;
    if (i < 98304) {
        const float v = (i < 32768) ? tw[i] : (i < 65536) ? pw[i - 32768] : gw[i - 65536];
        const unsigned short h = f2bfbits(v);
        wqh[i] = h;
        wql[i] = f2bfbits(v - bf2f(h));
    } else {
        const int j = i - 98304;
        const float v = ow[j];
        const unsigned short h = f2bfbits(v);
        woh[j] = h;
        wol[j] = f2bfbits(v - bf2f(h));
    }
}

// ---------------------------------------------------------------------------
// K1: FUSED transpose + theta/phi/g convs (pre-split weights).
// grid (128 nt of 64 n, 2 b), 512 thr = 8 waves. x read ONCE; no xT buffer.
// Each wave: 16 output channels for each of theta/phi/g (3 balanced tasks).
// Plain launch_bounds(512) — no VGPR cap (R7 lesson).
// ---------------------------------------------------------------------------
__global__ __launch_bounds__(512) void k_fused(
    const float* __restrict__ x,
    const unsigned short* __restrict__ wqh, const unsigned short* __restrict__ wql,
    const float* __restrict__ tb, const float* __restrict__ pb, const float* __restrict__ gb,
    unsigned short* __restrict__ thetaT, unsigned short* __restrict__ phiT,
    unsigned short* __restrict__ gT)
{
    __shared__ unsigned short xt[64 * 264];     // [n][c] bf16, pad 8
    __shared__ unsigned short parkP[64 * 136];  // [n][o] phi
    __shared__ unsigned short parkG[64 * 136];  // [n][o] g
    const int nt_ = blockIdx.x, b = blockIdx.y;
    const int nb = nt_ * 64;
    const int tid = threadIdx.x;

    // phase 1: x [c][n-tile] fp32 -> xt [n][c] bf16 (c-pair packed u32 writes)
    {
        const int j = tid & 127;            // c-pair (c = 2j, 2j+1)
        const int n16 = (tid >> 7) * 16;
        const float* r0 = x + ((size_t)(b * CC + 2 * j)) * NN + nb + n16;
        const float* r1 = r0 + NN;
        float v0[16], v1[16];
        *(float4*)&v0[0]  = *(const float4*)(r0);
        *(float4*)&v0[4]  = *(const float4*)(r0 + 4);
        *(float4*)&v0[8]  = *(const float4*)(r0 + 8);
        *(float4*)&v0[12] = *(const float4*)(r0 + 12);
        *(float4*)&v1[0]  = *(const float4*)(r1);
        *(float4*)&v1[4]  = *(const float4*)(r1 + 4);
        *(float4*)&v1[8]  = *(const float4*)(r1 + 8);
        *(float4*)&v1[12] = *(const float4*)(r1 + 12);
#pragma unroll
        for (int i = 0; i < 16; ++i) {
            const unsigned w = (unsigned)f2bfbits(v0[i]) | ((unsigned)f2bfbits(v1[i]) << 16);
            *(unsigned*)&xt[(n16 + i) * 264 + 2 * j] = w;
        }
    }
    __syncthreads();

    const int wave = tid >> 6, lane = tid & 63;
    const int lq = lane & 15, G = lane >> 4;
    const int ob = wave * 16;

#pragma unroll
    for (int sel = 0; sel < 3; ++sel) {
        const float* bias = (sel == 0) ? tb : (sel == 1) ? pb : gb;
        const int orow = sel * 128 + ob;

        f32x4 acc[4];
#pragma unroll
        for (int nt = 0; nt < 4; ++nt) acc[nt] = (f32x4){0.f, 0.f, 0.f, 0.f};

#pragma unroll
        for (int kc = 0; kc < 8; ++kc) {
            const size_t wr = (size_t)(orow + lq) * CC + kc * 32 + G * 8;
            const bf16x8 wh = *(const bf16x8*)(wqh + wr);
            const bf16x8 wl = *(const bf16x8*)(wql + wr);
#pragma unroll
            for (int nt = 0; nt < 4; ++nt) {
                const bf16x8 xf = *(const bf16x8*)&xt[(nt * 16 + lq) * 264 + kc * 32 + G * 8];
                acc[nt] = __builtin_amdgcn_mfma_f32_16x16x32_bf16(wh, xf, acc[nt], 0, 0, 0);
                acc[nt] = __builtin_amdgcn_mfma_f32_16x16x32_bf16(wl, xf, acc[nt], 0, 0, 0);
            }
        }
        const float4 bv = *(const float4*)&bias[ob + G * 4];
#pragma unroll
        for (int nt = 0; nt < 4; ++nt) {
            acc[nt][0] += bv.x; acc[nt][1] += bv.y;
            acc[nt][2] += bv.z; acc[nt][3] += bv.w;
        }

        if (sel == 0) {
#pragma unroll
            for (int nt = 0; nt < 4; ++nt) {
                unsigned short pk[4];
#pragma unroll
                for (int r = 0; r < 4; ++r) pk[r] = f2bfbits(acc[nt][r]);
                const int n = nb + nt * 16 + lq;
                *(uint2*)&thetaT[((size_t)b * NN + n) * CI + ob + G * 4] = *(uint2*)pk;
            }
        } else {
            unsigned short* park = (sel == 1) ? parkP : parkG;
#pragma unroll
            for (int nt = 0; nt < 4; ++nt) {
                unsigned short pk[4];
#pragma unroll
                for (int r = 0; r < 4; ++r) pk[r] = f2bfbits(acc[nt][r]);
                *(uint2*)&park[(nt * 16 + lq) * 136 + ob + G * 4] = *(uint2*)pk;
            }
        }
    }
    __syncthreads();

    // phase 3: 2x2 max-pool epilogues
    const int tfrm = nb >> 10, h0 = (nb >> 5) & 31;
    const int mb = tfrm * 256 + (h0 >> 1) * 16;
    for (int idx = tid; idx < 2048; idx += 512) {
        const int o = idx & 127, m = idx >> 7;
        const float v = fmaxf(
            fmaxf(bf2f(parkP[(2 * m) * 136 + o]), bf2f(parkP[(2 * m + 1) * 136 + o])),
            fmaxf(bf2f(parkP[(32 + 2 * m) * 136 + o]), bf2f(parkP[(33 + 2 * m) * 136 + o])));
        phiT[((size_t)b * MM + mb + m) * CI + o] = f2bfbits(v);
    }
    for (int idx = tid; idx < 2048; idx += 512) {
        const int o = idx >> 4, m = idx & 15;
        const float v = fmaxf(
            fmaxf(bf2f(parkG[(2 * m) * 136 + o]), bf2f(parkG[(2 * m + 1) * 136 + o])),
            fmaxf(bf2f(parkG[(32 + 2 * m) * 136 + o]), bf2f(parkG[(33 + 2 * m) * 136 + o])));
        gT[((size_t)b * CI + o) * MM + mb + m] = f2bfbits(v);
    }
}

// ---------------------------------------------------------------------------
// K2: flash attention, static-max  [R17, proven best]
// grid (64 qblk, 2 s, 2 b), 512 thr = 8 waves, 16 q/wave, KT=64 dbuf,
// per-t2 P double-buffer.
// ---------------------------------------------------------------------------
__global__ __launch_bounds__(512, 4) void k_attn(
    const unsigned short* __restrict__ thetaT,
    const unsigned short* __restrict__ phiT,
    const unsigned short* __restrict__ gT,
    unsigned short* __restrict__ yp,
    float* __restrict__ lbuf)
{
    __shared__ __align__(16) char smem[81920];  // 2 x (phi 16K + g 16K) + P 2x8K
    const int tid  = threadIdx.x;
    const int wave = tid >> 6;
    const int lane = tid & 63;
    const int lq = lane & 15, G = lane >> 4;
    const int qblk = blockIdx.x, s = blockIdx.y, b = blockIdx.z;
    const int qbase = qblk * 128 + wave * 16;
    const int koff0 = s * KSPAN;

    bf16x8 tf[4];
    {
        const size_t row = (size_t)b * NN + qbase + lq;
#pragma unroll
        for (int D = 0; D < 4; ++D)
            tf[D] = *(const bf16x8*)(thetaT + row * CI + D * 32 + G * 8);
    }

    const char* phiSrc = (const char*)(phiT + (size_t)b * MM * CI);
    const char* gSrc   = (const char*)(gT   + (size_t)b * CI * MM);
    int pk[2], pco[2];
#pragma unroll
    for (int i = 0; i < 2; ++i) {
        pk[i]  = wave * 8 + i * 4 + (lane >> 4);
        pco[i] = ((lane & 15) ^ (pk[i] & 7)) << 4;
    }
    const int gr0 = wave * 16 + (lane >> 3);
    const int u_  = lane & 7;
    const int gu  = (u_ & 4) | ((u_ & 3) ^ (gr0 & 3));

    auto STAGE = [&](int buf, int koff) {
        char* pl = smem + buf * 32768 + wave * 2048;
        char* gl = smem + buf * 32768 + 16384 + wave * 2048;
#pragma unroll
        for (int i = 0; i < 2; ++i) {
            gll16(phiSrc + (size_t)(koff + pk[i]) * 256 + pco[i], pl + i * 1024);
            gll16(gSrc + (size_t)(gr0 + i * 8) * 4096 + (size_t)koff * 2 + gu * 16, gl + i * 1024);
        }
    };

    f32x4 yacc[8];
#pragma unroll
    for (int c = 0; c < 8; ++c) yacc[c] = (f32x4){0.f, 0.f, 0.f, 0.f};
    float lreg = 0.f;

    STAGE(0, koff0);
    __syncthreads();

    char* pPb[2] = { smem + 65536 + wave * 1024, smem + 73728 + wave * 1024 };
    const int swq = (lq & 3) << 4;
    const int swk = (lq & 7) << 4;

    for (int ch = 0; ch < NCH; ++ch) {
        const int cur = ch & 1;
        if (ch < NCH - 1) STAGE(cur ^ 1, koff0 + (ch + 1) * KT);
        const char* pbuf = smem + cur * 32768;
        const char* gbuf = smem + cur * 32768 + 16384;

#pragma unroll
        for (int t2 = 0; t2 < 2; ++t2) {
            char* pP = pPb[t2];
            f32x4 sacc[2];
            sacc[0] = (f32x4){0.f, 0.f, 0.f, 0.f};
            sacc[1] = (f32x4){0.f, 0.f, 0.f, 0.f};
            __builtin_amdgcn_s_setprio(1);
#pragma unroll
            for (int D = 0; D < 4; ++D) {
                const int co = (((D * 4 + G) << 4) ^ swk);
                const bf16x8 a0 = *(const bf16x8*)(pbuf + (t2 * 32 + lq) * 256 + co);
                const bf16x8 a1 = *(const bf16x8*)(pbuf + (t2 * 32 + 16 + lq) * 256 + co);
                sacc[0] = __builtin_amdgcn_mfma_f32_16x16x32_bf16(a0, tf[D], sacc[0], 0, 0, 0);
                sacc[1] = __builtin_amdgcn_mfma_f32_16x16x32_bf16(a1, tf[D], sacc[1], 0, 0, 0);
            }
            __builtin_amdgcn_s_setprio(0);

            float p[8];
#pragma unroll
            for (int ks = 0; ks < 2; ++ks)
#pragma unroll
                for (int r = 0; r < 4; ++r) {
                    const float e = __expf(sacc[ks][r] - SUBC);
                    p[ks * 4 + r] = e;
                    lreg += e;
                }
#pragma unroll
            for (int ks = 0; ks < 2; ++ks)
#pragma unroll
                for (int r2 = 0; r2 < 2; ++r2) {
                    const unsigned w = (unsigned)f2bfbits(p[ks * 4 + r2 * 2]) |
                                       ((unsigned)f2bfbits(p[ks * 4 + r2 * 2 + 1]) << 16);
                    const int byt = (ks * 32 + G * 8 + r2 * 4) ^ swq;
                    *(unsigned*)(pP + lq * 64 + byt) = w;
                }

            const bf16x8 pf = *(const bf16x8*)(pP + lq * 64 + ((G * 16) ^ swq));
            __builtin_amdgcn_s_setprio(1);
#pragma unroll
            for (int c = 0; c < 8; ++c) {
                const int row = c * 16 + lq;
                const bf16x8 gf = *(const bf16x8*)(gbuf + row * 128 + t2 * 64 +
                                                   ((G * 16) ^ ((row & 3) << 4)));
                yacc[c] = __builtin_amdgcn_mfma_f32_16x16x32_bf16(gf, pf, yacc[c], 0, 0, 0);
            }
            __builtin_amdgcn_s_setprio(0);
        }
        __syncthreads();
    }

    lreg += __shfl_xor(lreg, 16);
    lreg += __shfl_xor(lreg, 32);

    const int sb = b * NSPLIT + s;
    if (lane < 16) lbuf[(size_t)sb * NN + qbase + lq] = lreg;
    const size_t nrow = ((size_t)sb * NN + qbase + lq) * CI;
#pragma unroll
    for (int c = 0; c < 8; ++c) {
        unsigned short pkk[4];
#pragma unroll
        for (int r = 0; r < 4; ++r) pkk[r] = f2bfbits(yacc[c][r]);
        *(uint2*)&yp[nrow + c * 16 + G * 4] = *(uint2*)pkk;
    }
}

// ---------------------------------------------------------------------------
// K3: output conv, fused combine, bf16 MFMA split-W + BN partial sums.
// [R17, proven; y2 bf16 in ws]
// grid (128 nt of 64 n, 2 cot, 2 b), 256 thr
// ---------------------------------------------------------------------------
__global__ __launch_bounds__(256, 2) void k_outconv(
    const unsigned short* __restrict__ yp, const float* __restrict__ lbuf,
    const unsigned short* __restrict__ woh, const unsigned short* __restrict__ wol,
    const float* __restrict__ obias, unsigned short* __restrict__ y2,
    float* __restrict__ psum, float* __restrict__ psq)
{
    const int nt_ = blockIdx.x, cot = blockIdx.y, b = blockIdx.z;
    const int nb = nt_ * 64;
    const int tid = threadIdx.x, wave = tid >> 6, lane = tid & 63;
    const int lq = lane & 15, G = lane >> 4;
    const int corow = cot * 128 + wave * 32;

    float inv[4];
#pragma unroll
    for (int nt = 0; nt < 4; ++nt) {
        const int n = nb + nt * 16 + lq;
        float l = 0.f;
#pragma unroll
        for (int s = 0; s < NSPLIT; ++s) l += lbuf[(size_t)(b * NSPLIT + s) * NN + n];
        inv[nt] = 1.f / l;
    }

    f32x4 acc[2][4];
#pragma unroll
    for (int ot = 0; ot < 2; ++ot)
#pragma unroll
        for (int nt = 0; nt < 4; ++nt) acc[ot][nt] = (f32x4){0.f, 0.f, 0.f, 0.f};

#pragma unroll
    for (int kc = 0; kc < 4; ++kc) {
        bf16x8 wh[2], wl[2];
#pragma unroll
        for (int ot = 0; ot < 2; ++ot) {
            const size_t wr = (size_t)(corow + ot * 16 + lq) * CI + kc * 32 + G * 8;
            wh[ot] = *(const bf16x8*)(woh + wr);
            wl[ot] = *(const bf16x8*)(wol + wr);
        }
#pragma unroll
        for (int s = 0; s < NSPLIT; ++s) {
            const unsigned short* xrow = yp + ((size_t)(b * NSPLIT + s) * NN + nb) * CI;
            bf16x8 xf[4];
#pragma unroll
            for (int nt = 0; nt < 4; ++nt)
                xf[nt] = *(const bf16x8*)(xrow + (size_t)(nt * 16 + lq) * CI + kc * 32 + G * 8);
#pragma unroll
            for (int ot = 0; ot < 2; ++ot)
#pragma unroll
                for (int nt = 0; nt < 4; ++nt) {
                    acc[ot][nt] = __builtin_amdgcn_mfma_f32_16x16x32_bf16(wh[ot], xf[nt], acc[ot][nt], 0, 0, 0);
                    acc[ot][nt] = __builtin_amdgcn_mfma_f32_16x16x32_bf16(wl[ot], xf[nt], acc[ot][nt], 0, 0, 0);
                }
        }
    }

#pragma unroll
    for (int ot = 0; ot < 2; ++ot) {
        const float4 bv = *(const float4*)&obias[corow + ot * 16 + G * 4];
#pragma unroll
        for (int nt = 0; nt < 4; ++nt) {
            acc[ot][nt][0] = acc[ot][nt][0] * inv[nt] + bv.x;
            acc[ot][nt][1] = acc[ot][nt][1] * inv[nt] + bv.y;
            acc[ot][nt][2] = acc[ot][nt][2] * inv[nt] + bv.z;
            acc[ot][nt][3] = acc[ot][nt][3] * inv[nt] + bv.w;
        }
    }

    // y2 [b][co][n] bf16 (stats below use fp32 acc, unaffected by rounding)
#pragma unroll
    for (int ot = 0; ot < 2; ++ot)
#pragma unroll
        for (int r = 0; r < 4; ++r) {
            const int co = corow + ot * 16 + G * 4 + r;
            unsigned short* dst = &y2[((size_t)b * CC + co) * NN + nb + lq];
#pragma unroll
            for (int nt = 0; nt < 4; ++nt) dst[nt * 16] = f2bfbits(acc[ot][nt][r]);
        }

#pragma unroll
    for (int ot = 0; ot < 2; ++ot)
#pragma unroll
        for (int r = 0; r < 4; ++r) {
            float sv = 0.f, q = 0.f;
#pragma unroll
            for (int nt = 0; nt < 4; ++nt) {
                const float v = acc[ot][nt][r];
                sv += v; q += v * v;
            }
#pragma unroll
            for (int d = 1; d < 16; d <<= 1) { sv += __shfl_xor(sv, d); q += __shfl_xor(q, d); }
            if (lq == 0) {
                const int co = corow + ot * 16 + G * 4 + r;
                psum[co * 256 + b * 128 + nt_] = sv;
                psq [co * 256 + b * 128 + nt_] = q;
            }
        }
}

// K4: reduce partials -> mean, inv_std
__global__ void k_red(const float* __restrict__ psum, const float* __restrict__ psq,
                      float* __restrict__ stats)
{
    const int co = threadIdx.x;
    float s = 0.f, q = 0.f;
    for (int i = 0; i < 256; ++i) { s += psum[co * 256 + i]; q += psq[co * 256 + i]; }
    const float mean = s * (1.f / 16384.f);
    const float var = q * (1.f / 16384.f) - mean * mean;
    stats[co] = mean;
    stats[256 + co] = rsqrtf(var + 1e-5f);
}

// K5: out = x + bn(y2) ; y2 bf16 from ws, out fp32 to d_out
__global__ __launch_bounds__(256) void k_bn(
    const float* __restrict__ x, const unsigned short* __restrict__ y2,
    const float* __restrict__ bw, const float* __restrict__ bb,
    const float* __restrict__ stats, float* __restrict__ out)
{
    const int i4 = blockIdx.x * 256 + threadIdx.x;
    const int c = (i4 >> 11) & 255;
    const float a = stats[256 + c] * bw[c];
    const float bias2 = bb[c] - stats[c] * a;
    const uint2 v2 = ((const uint2*)y2)[i4];
    const float4 xv = ((const float4*)x)[i4];
    float4 r;
    r.x = xv.x + bf2f((unsigned short)(v2.x & 0xffff)) * a + bias2;
    r.y = xv.y + bf2f((unsigned short)(v2.x >> 16))    * a + bias2;
    r.z = xv.z + bf2f((unsigned short)(v2.y & 0xffff)) * a + bias2;
    r.w = xv.w + bf2f((unsigned short)(v2.y >> 16))    * a + bias2;
    ((float4*)out)[i4] = r;
}

extern "C" void kernel_launch(void* const* d_in, const int* in_sizes, int n_in,
                              void* d_out, int out_size, void* d_ws, size_t ws_size,
                              hipStream_t stream) {
    const float* x       = (const float*)d_in[0];
    const float* g_w     = (const float*)d_in[1];
    const float* g_b     = (const float*)d_in[2];
    const float* theta_w = (const float*)d_in[3];
    const float* theta_b = (const float*)d_in[4];
    const float* phi_w   = (const float*)d_in[5];
    const float* phi_b   = (const float*)d_in[6];
    const float* out_w   = (const float*)d_in[7];
    const float* out_b   = (const float*)d_in[8];
    const float* bn_w    = (const float*)d_in[9];
    const float* bn_b    = (const float*)d_in[10];

    char* ws = (char*)d_ws;
    unsigned short* wqh     = (unsigned short*)(ws + OFF_WQH);
    unsigned short* wql     = (unsigned short*)(ws + OFF_WQL);
    unsigned short* woh     = (unsigned short*)(ws + OFF_WOH);
    unsigned short* wol     = (unsigned short*)(ws + OFF_WOL);
    unsigned short* theta16 = (unsigned short*)(ws + OFF_THETA16);
    unsigned short* phi16   = (unsigned short*)(ws + OFF_PHI16);
    unsigned short* g16     = (unsigned short*)(ws + OFF_G16);
    unsigned short* yp      = (unsigned short*)(ws + OFF_YP);
    unsigned short* y2      = (unsigned short*)(ws + OFF_Y2);
    float* lbuf  = (float*)(ws + OFF_LBUF);
    float* psum  = (float*)(ws + OFF_PSUM);
    float* psq   = (float*)(ws + OFF_PSQ);
    float* stats = (float*)(ws + OFF_STAT);
    float* out   = (float*)d_out;

    k_prep<<<dim3(256), 512, 0, stream>>>(theta_w, phi_w, g_w, out_w, wqh, wql, woh, wol);
    k_fused<<<dim3(128, 2), 512, 0, stream>>>(x, wqh, wql, theta_b, phi_b, g_b,
                                              theta16, phi16, g16);
    k_attn<<<dim3(64, NSPLIT, 2), 512, 0, stream>>>(theta16, phi16, g16, yp, lbuf);
    k_outconv<<<dim3(128, 2, 2), 256, 0, stream>>>(yp, lbuf, woh, wol, out_b, y2, psum, psq);
    k_red<<<1, 256, 0, stream>>>(psum, psq, stats);
    k_bn<<<4096, 256, 0, stream>>>(x, y2, bn_w, bn_b, stats, out);
}

// Round 19
// 86.462 us; speedup vs baseline: 1.3562x; 1.1629x over previous
//
#include <hip/hip_runtime.h>
#include <math.h>

#define CC 256
#define CI 128
#define NN 8192
#define MM 2048
#define NSPLIT 2
#define KSPAN 1024
#define KT 64
#define NCH 16
#define SUBC 20.0f
#define LOG2E 1.44269504088896340736f

typedef __attribute__((ext_vector_type(8))) short bf16x8;
typedef __attribute__((ext_vector_type(4))) float f32x4;

// ws byte offsets
#define OFF_WQH     8388608u
#define OFF_WQL     8585216u
#define OFF_WOH     8781824u
#define OFF_WOL     8847360u
#define OFF_THETA16 8912896u
#define OFF_PHI16   13107200u
#define OFF_G16     14155776u
#define OFF_YP      15204352u
#define OFF_LBUF    23592960u
#define OFF_PSUM    23724032u
#define OFF_PSQ     23986176u
#define OFF_STAT    24248320u
#define OFF_Y2      25165824u

static __device__ __forceinline__ unsigned short f2bfbits(float x) {
    unsigned u = __builtin_bit_cast(unsigned, x);
    u = u + 0x7fffu + ((u >> 16) & 1u);
    return (unsigned short)(u >> 16);
}
static __device__ __forceinline__ float bf2f(unsigned short h) {
    return __builtin_bit_cast(float, ((unsigned)h) << 16);
}
static __device__ __forceinline__ void gll16(const void* g, void* l) {
    __builtin_amdgcn_global_load_lds(
        (const __attribute__((address_space(1))) unsigned int*)g,
        (__attribute__((address_space(3))) unsigned int*)l, 16, 0, 0);
}

// ---------------------------------------------------------------------------
// K0: weight hi/lo split only.  grid (256), 512 thr (131072 elems exactly)
// ---------------------------------------------------------------------------
__global__ __launch_bounds__(512) void k_prep(
    const float* __restrict__ tw, const float* __restrict__ pw,
    const float* __restrict__ gw, const float* __restrict__ ow,
    unsigned short* __restrict__ wqh, unsigned short* __restrict__ wql,
    unsigned short* __restrict__ woh, unsigned short* __restrict__ wol)
{
    const int i = blockIdx.x * 512 + threadIdx.x;
    if (i < 98304) {
        const float v = (i < 32768) ? tw[i] : (i < 65536) ? pw[i - 32768] : gw[i - 65536];
        const unsigned short h = f2bfbits(v);
        wqh[i] = h;
        wql[i] = f2bfbits(v - bf2f(h));
    } else {
        const int j = i - 98304;
        const float v = ow[j];
        const unsigned short h = f2bfbits(v);
        woh[j] = h;
        wol[j] = f2bfbits(v - bf2f(h));
    }
}

// ---------------------------------------------------------------------------
// K1: FUSED transpose + theta/phi/g convs (pre-split weights).  [R18, proven]
// grid (128 nt of 64 n, 2 b), 512 thr = 8 waves. x read ONCE; no xT buffer.
// ---------------------------------------------------------------------------
__global__ __launch_bounds__(512) void k_fused(
    const float* __restrict__ x,
    const unsigned short* __restrict__ wqh, const unsigned short* __restrict__ wql,
    const float* __restrict__ tb, const float* __restrict__ pb, const float* __restrict__ gb,
    unsigned short* __restrict__ thetaT, unsigned short* __restrict__ phiT,
    unsigned short* __restrict__ gT)
{
    __shared__ unsigned short xt[64 * 264];     // [n][c] bf16, pad 8
    __shared__ unsigned short parkP[64 * 136];  // [n][o] phi
    __shared__ unsigned short parkG[64 * 136];  // [n][o] g
    const int nt_ = blockIdx.x, b = blockIdx.y;
    const int nb = nt_ * 64;
    const int tid = threadIdx.x;

    // phase 1: x [c][n-tile] fp32 -> xt [n][c] bf16
    {
        const int j = tid & 127;            // c-pair (c = 2j, 2j+1)
        const int n16 = (tid >> 7) * 16;
        const float* r0 = x + ((size_t)(b * CC + 2 * j)) * NN + nb + n16;
        const float* r1 = r0 + NN;
        float v0[16], v1[16];
        *(float4*)&v0[0]  = *(const float4*)(r0);
        *(float4*)&v0[4]  = *(const float4*)(r0 + 4);
        *(float4*)&v0[8]  = *(const float4*)(r0 + 8);
        *(float4*)&v0[12] = *(const float4*)(r0 + 12);
        *(float4*)&v1[0]  = *(const float4*)(r1);
        *(float4*)&v1[4]  = *(const float4*)(r1 + 4);
        *(float4*)&v1[8]  = *(const float4*)(r1 + 8);
        *(float4*)&v1[12] = *(const float4*)(r1 + 12);
#pragma unroll
        for (int i = 0; i < 16; ++i) {
            const unsigned w = (unsigned)f2bfbits(v0[i]) | ((unsigned)f2bfbits(v1[i]) << 16);
            *(unsigned*)&xt[(n16 + i) * 264 + 2 * j] = w;
        }
    }
    __syncthreads();

    const int wave = tid >> 6, lane = tid & 63;
    const int lq = lane & 15, G = lane >> 4;
    const int ob = wave * 16;

#pragma unroll
    for (int sel = 0; sel < 3; ++sel) {
        const float* bias = (sel == 0) ? tb : (sel == 1) ? pb : gb;
        const int orow = sel * 128 + ob;

        f32x4 acc[4];
#pragma unroll
        for (int nt = 0; nt < 4; ++nt) acc[nt] = (f32x4){0.f, 0.f, 0.f, 0.f};

#pragma unroll
        for (int kc = 0; kc < 8; ++kc) {
            const size_t wr = (size_t)(orow + lq) * CC + kc * 32 + G * 8;
            const bf16x8 wh = *(const bf16x8*)(wqh + wr);
            const bf16x8 wl = *(const bf16x8*)(wql + wr);
#pragma unroll
            for (int nt = 0; nt < 4; ++nt) {
                const bf16x8 xf = *(const bf16x8*)&xt[(nt * 16 + lq) * 264 + kc * 32 + G * 8];
                acc[nt] = __builtin_amdgcn_mfma_f32_16x16x32_bf16(wh, xf, acc[nt], 0, 0, 0);
                acc[nt] = __builtin_amdgcn_mfma_f32_16x16x32_bf16(wl, xf, acc[nt], 0, 0, 0);
            }
        }
        const float4 bv = *(const float4*)&bias[ob + G * 4];
#pragma unroll
        for (int nt = 0; nt < 4; ++nt) {
            acc[nt][0] += bv.x; acc[nt][1] += bv.y;
            acc[nt][2] += bv.z; acc[nt][3] += bv.w;
        }

        if (sel == 0) {
#pragma unroll
            for (int nt = 0; nt < 4; ++nt) {
                unsigned short pk[4];
#pragma unroll
                for (int r = 0; r < 4; ++r) pk[r] = f2bfbits(acc[nt][r]);
                const int n = nb + nt * 16 + lq;
                *(uint2*)&thetaT[((size_t)b * NN + n) * CI + ob + G * 4] = *(uint2*)pk;
            }
        } else {
            unsigned short* park = (sel == 1) ? parkP : parkG;
#pragma unroll
            for (int nt = 0; nt < 4; ++nt) {
                unsigned short pk[4];
#pragma unroll
                for (int r = 0; r < 4; ++r) pk[r] = f2bfbits(acc[nt][r]);
                *(uint2*)&park[(nt * 16 + lq) * 136 + ob + G * 4] = *(uint2*)pk;
            }
        }
    }
    __syncthreads();

    // phase 3: 2x2 max-pool epilogues
    const int tfrm = nb >> 10, h0 = (nb >> 5) & 31;
    const int mb = tfrm * 256 + (h0 >> 1) * 16;
    for (int idx = tid; idx < 2048; idx += 512) {
        const int o = idx & 127, m = idx >> 7;
        const float v = fmaxf(
            fmaxf(bf2f(parkP[(2 * m) * 136 + o]), bf2f(parkP[(2 * m + 1) * 136 + o])),
            fmaxf(bf2f(parkP[(32 + 2 * m) * 136 + o]), bf2f(parkP[(33 + 2 * m) * 136 + o])));
        phiT[((size_t)b * MM + mb + m) * CI + o] = f2bfbits(v);
    }
    for (int idx = tid; idx < 2048; idx += 512) {
        const int o = idx >> 4, m = idx & 15;
        const float v = fmaxf(
            fmaxf(bf2f(parkG[(2 * m) * 136 + o]), bf2f(parkG[(2 * m + 1) * 136 + o])),
            fmaxf(bf2f(parkG[(32 + 2 * m) * 136 + o]), bf2f(parkG[(33 + 2 * m) * 136 + o])));
        gT[((size_t)b * CI + o) * MM + mb + m] = f2bfbits(v);
    }
}

// ---------------------------------------------------------------------------
// K2: flash attention, static-max  [R17/R18 + exp2 fma on softmax chain]
// grid (64 qblk, 2 s, 2 b), 512 thr = 8 waves, 16 q/wave, KT=64 dbuf,
// per-t2 P double-buffer.
// ---------------------------------------------------------------------------
__global__ __launch_bounds__(512, 4) void k_attn(
    const unsigned short* __restrict__ thetaT,
    const unsigned short* __restrict__ phiT,
    const unsigned short* __restrict__ gT,
    unsigned short* __restrict__ yp,
    float* __restrict__ lbuf)
{
    __shared__ __align__(16) char smem[81920];  // 2 x (phi 16K + g 16K) + P 2x8K
    const int tid  = threadIdx.x;
    const int wave = tid >> 6;
    const int lane = tid & 63;
    const int lq = lane & 15, G = lane >> 4;
    const int qblk = blockIdx.x, s = blockIdx.y, b = blockIdx.z;
    const int qbase = qblk * 128 + wave * 16;
    const int koff0 = s * KSPAN;

    bf16x8 tf[4];
    {
        const size_t row = (size_t)b * NN + qbase + lq;
#pragma unroll
        for (int D = 0; D < 4; ++D)
            tf[D] = *(const bf16x8*)(thetaT + row * CI + D * 32 + G * 8);
    }

    const char* phiSrc = (const char*)(phiT + (size_t)b * MM * CI);
    const char* gSrc   = (const char*)(gT   + (size_t)b * CI * MM);
    int pk[2], pco[2];
#pragma unroll
    for (int i = 0; i < 2; ++i) {
        pk[i]  = wave * 8 + i * 4 + (lane >> 4);
        pco[i] = ((lane & 15) ^ (pk[i] & 7)) << 4;
    }
    const int gr0 = wave * 16 + (lane >> 3);
    const int u_  = lane & 7;
    const int gu  = (u_ & 4) | ((u_ & 3) ^ (gr0 & 3));

    auto STAGE = [&](int buf, int koff) {
        char* pl = smem + buf * 32768 + wave * 2048;
        char* gl = smem + buf * 32768 + 16384 + wave * 2048;
#pragma unroll
        for (int i = 0; i < 2; ++i) {
            gll16(phiSrc + (size_t)(koff + pk[i]) * 256 + pco[i], pl + i * 1024);
            gll16(gSrc + (size_t)(gr0 + i * 8) * 4096 + (size_t)koff * 2 + gu * 16, gl + i * 1024);
        }
    };

    f32x4 yacc[8];
#pragma unroll
    for (int c = 0; c < 8; ++c) yacc[c] = (f32x4){0.f, 0.f, 0.f, 0.f};
    float lreg = 0.f;

    STAGE(0, koff0);
    __syncthreads();

    char* pPb[2] = { smem + 65536 + wave * 1024, smem + 73728 + wave * 1024 };
    const int swq = (lq & 3) << 4;
    const int swk = (lq & 7) << 4;

    for (int ch = 0; ch < NCH; ++ch) {
        const int cur = ch & 1;
        if (ch < NCH - 1) STAGE(cur ^ 1, koff0 + (ch + 1) * KT);
        const char* pbuf = smem + cur * 32768;
        const char* gbuf = smem + cur * 32768 + 16384;

#pragma unroll
        for (int t2 = 0; t2 < 2; ++t2) {
            char* pP = pPb[t2];
            f32x4 sacc[2];
            sacc[0] = (f32x4){0.f, 0.f, 0.f, 0.f};
            sacc[1] = (f32x4){0.f, 0.f, 0.f, 0.f};
            __builtin_amdgcn_s_setprio(1);
#pragma unroll
            for (int D = 0; D < 4; ++D) {
                const int co = (((D * 4 + G) << 4) ^ swk);
                const bf16x8 a0 = *(const bf16x8*)(pbuf + (t2 * 32 + lq) * 256 + co);
                const bf16x8 a1 = *(const bf16x8*)(pbuf + (t2 * 32 + 16 + lq) * 256 + co);
                sacc[0] = __builtin_amdgcn_mfma_f32_16x16x32_bf16(a0, tf[D], sacc[0], 0, 0, 0);
                sacc[1] = __builtin_amdgcn_mfma_f32_16x16x32_bf16(a1, tf[D], sacc[1], 0, 0, 0);
            }
            __builtin_amdgcn_s_setprio(0);

            // p = exp(s - SUBC) = exp2(s*log2e - SUBC*log2e)  (fma + v_exp)
            float p[8];
#pragma unroll
            for (int ks = 0; ks < 2; ++ks)
#pragma unroll
                for (int r = 0; r < 4; ++r) {
                    const float e = exp2f(fmaf(sacc[ks][r], LOG2E, -SUBC * LOG2E));
                    p[ks * 4 + r] = e;
                    lreg += e;
                }
#pragma unroll
            for (int ks = 0; ks < 2; ++ks)
#pragma unroll
                for (int r2 = 0; r2 < 2; ++r2) {
                    const unsigned w = (unsigned)f2bfbits(p[ks * 4 + r2 * 2]) |
                                       ((unsigned)f2bfbits(p[ks * 4 + r2 * 2 + 1]) << 16);
                    const int byt = (ks * 32 + G * 8 + r2 * 4) ^ swq;
                    *(unsigned*)(pP + lq * 64 + byt) = w;
                }

            const bf16x8 pf = *(const bf16x8*)(pP + lq * 64 + ((G * 16) ^ swq));
            __builtin_amdgcn_s_setprio(1);
#pragma unroll
            for (int c = 0; c < 8; ++c) {
                const int row = c * 16 + lq;
                const bf16x8 gf = *(const bf16x8*)(gbuf + row * 128 + t2 * 64 +
                                                   ((G * 16) ^ ((row & 3) << 4)));
                yacc[c] = __builtin_amdgcn_mfma_f32_16x16x32_bf16(gf, pf, yacc[c], 0, 0, 0);
            }
            __builtin_amdgcn_s_setprio(0);
        }
        __syncthreads();
    }

    lreg += __shfl_xor(lreg, 16);
    lreg += __shfl_xor(lreg, 32);

    const int sb = b * NSPLIT + s;
    if (lane < 16) lbuf[(size_t)sb * NN + qbase + lq] = lreg;
    const size_t nrow = ((size_t)sb * NN + qbase + lq) * CI;
#pragma unroll
    for (int c = 0; c < 8; ++c) {
        unsigned short pkk[4];
#pragma unroll
        for (int r = 0; r < 4; ++r) pkk[r] = f2bfbits(yacc[c][r]);
        *(uint2*)&yp[nrow + c * 16 + G * 4] = *(uint2*)pkk;
    }
}

// ---------------------------------------------------------------------------
// K3: output conv, fused combine, bf16 MFMA split-W + BN partial sums.
// [R17/R18, proven; y2 bf16 in ws]
// grid (128 nt of 64 n, 2 cot, 2 b), 256 thr
// ---------------------------------------------------------------------------
__global__ __launch_bounds__(256, 2) void k_outconv(
    const unsigned short* __restrict__ yp, const float* __restrict__ lbuf,
    const unsigned short* __restrict__ woh, const unsigned short* __restrict__ wol,
    const float* __restrict__ obias, unsigned short* __restrict__ y2,
    float* __restrict__ psum, float* __restrict__ psq)
{
    const int nt_ = blockIdx.x, cot = blockIdx.y, b = blockIdx.z;
    const int nb = nt_ * 64;
    const int tid = threadIdx.x, wave = tid >> 6, lane = tid & 63;
    const int lq = lane & 15, G = lane >> 4;
    const int corow = cot * 128 + wave * 32;

    float inv[4];
#pragma unroll
    for (int nt = 0; nt < 4; ++nt) {
        const int n = nb + nt * 16 + lq;
        float l = 0.f;
#pragma unroll
        for (int s = 0; s < NSPLIT; ++s) l += lbuf[(size_t)(b * NSPLIT + s) * NN + n];
        inv[nt] = 1.f / l;
    }

    f32x4 acc[2][4];
#pragma unroll
    for (int ot = 0; ot < 2; ++ot)
#pragma unroll
        for (int nt = 0; nt < 4; ++nt) acc[ot][nt] = (f32x4){0.f, 0.f, 0.f, 0.f};

#pragma unroll
    for (int kc = 0; kc < 4; ++kc) {
        bf16x8 wh[2], wl[2];
#pragma unroll
        for (int ot = 0; ot < 2; ++ot) {
            const size_t wr = (size_t)(corow + ot * 16 + lq) * CI + kc * 32 + G * 8;
            wh[ot] = *(const bf16x8*)(woh + wr);
            wl[ot] = *(const bf16x8*)(wol + wr);
        }
#pragma unroll
        for (int s = 0; s < NSPLIT; ++s) {
            const unsigned short* xrow = yp + ((size_t)(b * NSPLIT + s) * NN + nb) * CI;
            bf16x8 xf[4];
#pragma unroll
            for (int nt = 0; nt < 4; ++nt)
                xf[nt] = *(const bf16x8*)(xrow + (size_t)(nt * 16 + lq) * CI + kc * 32 + G * 8);
#pragma unroll
            for (int ot = 0; ot < 2; ++ot)
#pragma unroll
                for (int nt = 0; nt < 4; ++nt) {
                    acc[ot][nt] = __builtin_amdgcn_mfma_f32_16x16x32_bf16(wh[ot], xf[nt], acc[ot][nt], 0, 0, 0);
                    acc[ot][nt] = __builtin_amdgcn_mfma_f32_16x16x32_bf16(wl[ot], xf[nt], acc[ot][nt], 0, 0, 0);
                }
        }
    }

#pragma unroll
    for (int ot = 0; ot < 2; ++ot) {
        const float4 bv = *(const float4*)&obias[corow + ot * 16 + G * 4];
#pragma unroll
        for (int nt = 0; nt < 4; ++nt) {
            acc[ot][nt][0] = acc[ot][nt][0] * inv[nt] + bv.x;
            acc[ot][nt][1] = acc[ot][nt][1] * inv[nt] + bv.y;
            acc[ot][nt][2] = acc[ot][nt][2] * inv[nt] + bv.z;
            acc[ot][nt][3] = acc[ot][nt][3] * inv[nt] + bv.w;
        }
    }

    // y2 [b][co][n] bf16 (stats below use fp32 acc, unaffected by rounding)
#pragma unroll
    for (int ot = 0; ot < 2; ++ot)
#pragma unroll
        for (int r = 0; r < 4; ++r) {
            const int co = corow + ot * 16 + G * 4 + r;
            unsigned short* dst = &y2[((size_t)b * CC + co) * NN + nb + lq];
#pragma unroll
            for (int nt = 0; nt < 4; ++nt) dst[nt * 16] = f2bfbits(acc[ot][nt][r]);
        }

#pragma unroll
    for (int ot = 0; ot < 2; ++ot)
#pragma unroll
        for (int r = 0; r < 4; ++r) {
            float sv = 0.f, q = 0.f;
#pragma unroll
            for (int nt = 0; nt < 4; ++nt) {
                const float v = acc[ot][nt][r];
                sv += v; q += v * v;
            }
#pragma unroll
            for (int d = 1; d < 16; d <<= 1) { sv += __shfl_xor(sv, d); q += __shfl_xor(q, d); }
            if (lq == 0) {
                const int co = corow + ot * 16 + G * 4 + r;
                psum[co * 256 + b * 128 + nt_] = sv;
                psq [co * 256 + b * 128 + nt_] = q;
            }
        }
}

// ---------------------------------------------------------------------------
// K4: reduce partials -> mean, inv_std.  Parallel: grid (256) blocks (one
// channel each), 256 thr, shuffle+LDS tree reduce.
// ---------------------------------------------------------------------------
__global__ __launch_bounds__(256) void k_red(
    const float* __restrict__ psum, const float* __restrict__ psq,
    float* __restrict__ stats)
{
    __shared__ float ssum[4], ssq[4];
    const int co = blockIdx.x;
    const int t = threadIdx.x;
    float s = psum[co * 256 + t];
    float q = psq [co * 256 + t];
#pragma unroll
    for (int d = 1; d < 64; d <<= 1) { s += __shfl_xor(s, d); q += __shfl_xor(q, d); }
    if ((t & 63) == 0) { ssum[t >> 6] = s; ssq[t >> 6] = q; }
    __syncthreads();
    if (t == 0) {
        const float st = ssum[0] + ssum[1] + ssum[2] + ssum[3];
        const float qt = ssq[0] + ssq[1] + ssq[2] + ssq[3];
        const float mean = st * (1.f / 16384.f);
        const float var = qt * (1.f / 16384.f) - mean * mean;
        stats[co] = mean;
        stats[256 + co] = rsqrtf(var + 1e-5f);
    }
}

// K5: out = x + bn(y2) ; y2 bf16 from ws, out fp32 to d_out
__global__ __launch_bounds__(256) void k_bn(
    const float* __restrict__ x, const unsigned short* __restrict__ y2,
    const float* __restrict__ bw, const float* __restrict__ bb,
    const float* __restrict__ stats, float* __restrict__ out)
{
    const int i4 = blockIdx.x * 256 + threadIdx.x;
    const int c = (i4 >> 11) & 255;
    const float a = stats[256 + c] * bw[c];
    const float bias2 = bb[c] - stats[c] * a;
    const uint2 v2 = ((const uint2*)y2)[i4];
    const float4 xv = ((const float4*)x)[i4];
    float4 r;
    r.x = xv.x + bf2f((unsigned short)(v2.x & 0xffff)) * a + bias2;
    r.y = xv.y + bf2f((unsigned short)(v2.x >> 16))    * a + bias2;
    r.z = xv.z + bf2f((unsigned short)(v2.y & 0xffff)) * a + bias2;
    r.w = xv.w + bf2f((unsigned short)(v2.y >> 16))    * a + bias2;
    ((float4*)out)[i4] = r;
}

extern "C" void kernel_launch(void* const* d_in, const int* in_sizes, int n_in,
                              void* d_out, int out_size, void* d_ws, size_t ws_size,
                              hipStream_t stream) {
    const float* x       = (const float*)d_in[0];
    const float* g_w     = (const float*)d_in[1];
    const float* g_b     = (const float*)d_in[2];
    const float* theta_w = (const float*)d_in[3];
    const float* theta_b = (const float*)d_in[4];
    const float* phi_w   = (const float*)d_in[5];
    const float* phi_b   = (const float*)d_in[6];
    const float* out_w   = (const float*)d_in[7];
    const float* out_b   = (const float*)d_in[8];
    const float* bn_w    = (const float*)d_in[9];
    const float* bn_b    = (const float*)d_in[10];

    char* ws = (char*)d_ws;
    unsigned short* wqh     = (unsigned short*)(ws + OFF_WQH);
    unsigned short* wql     = (unsigned short*)(ws + OFF_WQL);
    unsigned short* woh     = (unsigned short*)(ws + OFF_WOH);
    unsigned short* wol     = (unsigned short*)(ws + OFF_WOL);
    unsigned short* theta16 = (unsigned short*)(ws + OFF_THETA16);
    unsigned short* phi16   = (unsigned short*)(ws + OFF_PHI16);
    unsigned short* g16     = (unsigned short*)(ws + OFF_G16);
    unsigned short* yp      = (unsigned short*)(ws + OFF_YP);
    unsigned short* y2      = (unsigned short*)(ws + OFF_Y2);
    float* lbuf  = (float*)(ws + OFF_LBUF);
    float* psum  = (float*)(ws + OFF_PSUM);
    float* psq   = (float*)(ws + OFF_PSQ);
    float* stats = (float*)(ws + OFF_STAT);
    float* out   = (float*)d_out;

    k_prep<<<dim3(256), 512, 0, stream>>>(theta_w, phi_w, g_w, out_w, wqh, wql, woh, wol);
    k_fused<<<dim3(128, 2), 512, 0, stream>>>(x, wqh, wql, theta_b, phi_b, g_b,
                                              theta16, phi16, g16);
    k_attn<<<dim3(64, NSPLIT, 2), 512, 0, stream>>>(theta16, phi16, g16, yp, lbuf);
    k_outconv<<<dim3(128, 2, 2), 256, 0, stream>>>(yp, lbuf, woh, wol, out_b, y2, psum, psq);
    k_red<<<256, 256, 0, stream>>>(psum, psq, stats);
    k_bn<<<4096, 256, 0, stream>>>(x, y2, bn_w, bn_b, stats, out);
}

// Round 20
// 85.310 us; speedup vs baseline: 1.3745x; 1.0135x over previous
//
#include <hip/hip_runtime.h>
#include <math.h>

#define CC 256
#define CI 128
#define NN 8192
#define MM 2048
#define NSPLIT 2
#define KSPAN 1024
#define KT 64
#define NCH 16
#define SUBC 20.0f
#define LOG2E 1.44269504088896340736f

typedef __attribute__((ext_vector_type(8))) short bf16x8;
typedef __attribute__((ext_vector_type(4))) float f32x4;

// ws byte offsets
#define OFF_WQH     8388608u
#define OFF_WQL     8585216u
#define OFF_WOH     8781824u
#define OFF_WOL     8847360u
#define OFF_THETA16 8912896u
#define OFF_PHI16   13107200u
#define OFF_G16     14155776u
#define OFF_YP      15204352u
#define OFF_LBUF    23592960u
#define OFF_PSUM    23724032u
#define OFF_PSQ     23986176u
#define OFF_STAT    24248320u
#define OFF_Y2      25165824u

static __device__ __forceinline__ unsigned short f2bfbits(float x) {
    unsigned u = __builtin_bit_cast(unsigned, x);
    u = u + 0x7fffu + ((u >> 16) & 1u);
    return (unsigned short)(u >> 16);
}
static __device__ __forceinline__ float bf2f(unsigned short h) {
    return __builtin_bit_cast(float, ((unsigned)h) << 16);
}
static __device__ __forceinline__ void gll16(const void* g, void* l) {
    __builtin_amdgcn_global_load_lds(
        (const __attribute__((address_space(1))) unsigned int*)g,
        (__attribute__((address_space(3))) unsigned int*)l, 16, 0, 0);
}

// ---------------------------------------------------------------------------
// K0: weight hi/lo split only.  grid (256), 512 thr (131072 elems exactly)
// ---------------------------------------------------------------------------
__global__ __launch_bounds__(512) void k_prep(
    const float* __restrict__ tw, const float* __restrict__ pw,
    const float* __restrict__ gw, const float* __restrict__ ow,
    unsigned short* __restrict__ wqh, unsigned short* __restrict__ wql,
    unsigned short* __restrict__ woh, unsigned short* __restrict__ wol)
{
    const int i = blockIdx.x * 512 + threadIdx.x;
    if (i < 98304) {
        const float v = (i < 32768) ? tw[i] : (i < 65536) ? pw[i - 32768] : gw[i - 65536];
        const unsigned short h = f2bfbits(v);
        wqh[i] = h;
        wql[i] = f2bfbits(v - bf2f(h));
    } else {
        const int j = i - 98304;
        const float v = ow[j];
        const unsigned short h = f2bfbits(v);
        woh[j] = h;
        wol[j] = f2bfbits(v - bf2f(h));
    }
}

// ---------------------------------------------------------------------------
// K1: FUSED transpose + theta/phi/g convs (pre-split weights).  [R18/R19]
// grid (128 nt of 64 n, 2 b), 512 thr = 8 waves. x read ONCE; no xT buffer.
// ---------------------------------------------------------------------------
__global__ __launch_bounds__(512) void k_fused(
    const float* __restrict__ x,
    const unsigned short* __restrict__ wqh, const unsigned short* __restrict__ wql,
    const float* __restrict__ tb, const float* __restrict__ pb, const float* __restrict__ gb,
    unsigned short* __restrict__ thetaT, unsigned short* __restrict__ phiT,
    unsigned short* __restrict__ gT)
{
    __shared__ unsigned short xt[64 * 264];     // [n][c] bf16, pad 8
    __shared__ unsigned short parkP[64 * 136];  // [n][o] phi
    __shared__ unsigned short parkG[64 * 136];  // [n][o] g
    const int nt_ = blockIdx.x, b = blockIdx.y;
    const int nb = nt_ * 64;
    const int tid = threadIdx.x;

    // phase 1: x [c][n-tile] fp32 -> xt [n][c] bf16
    {
        const int j = tid & 127;            // c-pair (c = 2j, 2j+1)
        const int n16 = (tid >> 7) * 16;
        const float* r0 = x + ((size_t)(b * CC + 2 * j)) * NN + nb + n16;
        const float* r1 = r0 + NN;
        float v0[16], v1[16];
        *(float4*)&v0[0]  = *(const float4*)(r0);
        *(float4*)&v0[4]  = *(const float4*)(r0 + 4);
        *(float4*)&v0[8]  = *(const float4*)(r0 + 8);
        *(float4*)&v0[12] = *(const float4*)(r0 + 12);
        *(float4*)&v1[0]  = *(const float4*)(r1);
        *(float4*)&v1[4]  = *(const float4*)(r1 + 4);
        *(float4*)&v1[8]  = *(const float4*)(r1 + 8);
        *(float4*)&v1[12] = *(const float4*)(r1 + 12);
#pragma unroll
        for (int i = 0; i < 16; ++i) {
            const unsigned w = (unsigned)f2bfbits(v0[i]) | ((unsigned)f2bfbits(v1[i]) << 16);
            *(unsigned*)&xt[(n16 + i) * 264 + 2 * j] = w;
        }
    }
    __syncthreads();

    const int wave = tid >> 6, lane = tid & 63;
    const int lq = lane & 15, G = lane >> 4;
    const int ob = wave * 16;

#pragma unroll
    for (int sel = 0; sel < 3; ++sel) {
        const float* bias = (sel == 0) ? tb : (sel == 1) ? pb : gb;
        const int orow = sel * 128 + ob;

        f32x4 acc[4];
#pragma unroll
        for (int nt = 0; nt < 4; ++nt) acc[nt] = (f32x4){0.f, 0.f, 0.f, 0.f};

#pragma unroll
        for (int kc = 0; kc < 8; ++kc) {
            const size_t wr = (size_t)(orow + lq) * CC + kc * 32 + G * 8;
            const bf16x8 wh = *(const bf16x8*)(wqh + wr);
            const bf16x8 wl = *(const bf16x8*)(wql + wr);
#pragma unroll
            for (int nt = 0; nt < 4; ++nt) {
                const bf16x8 xf = *(const bf16x8*)&xt[(nt * 16 + lq) * 264 + kc * 32 + G * 8];
                acc[nt] = __builtin_amdgcn_mfma_f32_16x16x32_bf16(wh, xf, acc[nt], 0, 0, 0);
                acc[nt] = __builtin_amdgcn_mfma_f32_16x16x32_bf16(wl, xf, acc[nt], 0, 0, 0);
            }
        }
        const float4 bv = *(const float4*)&bias[ob + G * 4];
#pragma unroll
        for (int nt = 0; nt < 4; ++nt) {
            acc[nt][0] += bv.x; acc[nt][1] += bv.y;
            acc[nt][2] += bv.z; acc[nt][3] += bv.w;
        }

        if (sel == 0) {
#pragma unroll
            for (int nt = 0; nt < 4; ++nt) {
                unsigned short pk[4];
#pragma unroll
                for (int r = 0; r < 4; ++r) pk[r] = f2bfbits(acc[nt][r]);
                const int n = nb + nt * 16 + lq;
                *(uint2*)&thetaT[((size_t)b * NN + n) * CI + ob + G * 4] = *(uint2*)pk;
            }
        } else {
            unsigned short* park = (sel == 1) ? parkP : parkG;
#pragma unroll
            for (int nt = 0; nt < 4; ++nt) {
                unsigned short pk[4];
#pragma unroll
                for (int r = 0; r < 4; ++r) pk[r] = f2bfbits(acc[nt][r]);
                *(uint2*)&park[(nt * 16 + lq) * 136 + ob + G * 4] = *(uint2*)pk;
            }
        }
    }
    __syncthreads();

    // phase 3: 2x2 max-pool epilogues
    const int tfrm = nb >> 10, h0 = (nb >> 5) & 31;
    const int mb = tfrm * 256 + (h0 >> 1) * 16;
    for (int idx = tid; idx < 2048; idx += 512) {
        const int o = idx & 127, m = idx >> 7;
        const float v = fmaxf(
            fmaxf(bf2f(parkP[(2 * m) * 136 + o]), bf2f(parkP[(2 * m + 1) * 136 + o])),
            fmaxf(bf2f(parkP[(32 + 2 * m) * 136 + o]), bf2f(parkP[(33 + 2 * m) * 136 + o])));
        phiT[((size_t)b * MM + mb + m) * CI + o] = f2bfbits(v);
    }
    for (int idx = tid; idx < 2048; idx += 512) {
        const int o = idx >> 4, m = idx & 15;
        const float v = fmaxf(
            fmaxf(bf2f(parkG[(2 * m) * 136 + o]), bf2f(parkG[(2 * m + 1) * 136 + o])),
            fmaxf(bf2f(parkG[(32 + 2 * m) * 136 + o]), bf2f(parkG[(33 + 2 * m) * 136 + o])));
        gT[((size_t)b * CI + o) * MM + mb + m] = f2bfbits(v);
    }
}

// ---------------------------------------------------------------------------
// K2: flash attention, static-max  [R19 + truncation P-pack]
// grid (64 qblk, 2 s, 2 b), 512 thr = 8 waves, 16 q/wave, KT=64 dbuf,
// per-t2 P double-buffer, exp2-fma softmax.
// ---------------------------------------------------------------------------
__global__ __launch_bounds__(512, 4) void k_attn(
    const unsigned short* __restrict__ thetaT,
    const unsigned short* __restrict__ phiT,
    const unsigned short* __restrict__ gT,
    unsigned short* __restrict__ yp,
    float* __restrict__ lbuf)
{
    __shared__ __align__(16) char smem[81920];  // 2 x (phi 16K + g 16K) + P 2x8K
    const int tid  = threadIdx.x;
    const int wave = tid >> 6;
    const int lane = tid & 63;
    const int lq = lane & 15, G = lane >> 4;
    const int qblk = blockIdx.x, s = blockIdx.y, b = blockIdx.z;
    const int qbase = qblk * 128 + wave * 16;
    const int koff0 = s * KSPAN;

    bf16x8 tf[4];
    {
        const size_t row = (size_t)b * NN + qbase + lq;
#pragma unroll
        for (int D = 0; D < 4; ++D)
            tf[D] = *(const bf16x8*)(thetaT + row * CI + D * 32 + G * 8);
    }

    const char* phiSrc = (const char*)(phiT + (size_t)b * MM * CI);
    const char* gSrc   = (const char*)(gT   + (size_t)b * CI * MM);
    int pk[2], pco[2];
#pragma unroll
    for (int i = 0; i < 2; ++i) {
        pk[i]  = wave * 8 + i * 4 + (lane >> 4);
        pco[i] = ((lane & 15) ^ (pk[i] & 7)) << 4;
    }
    const int gr0 = wave * 16 + (lane >> 3);
    const int u_  = lane & 7;
    const int gu  = (u_ & 4) | ((u_ & 3) ^ (gr0 & 3));

    auto STAGE = [&](int buf, int koff) {
        char* pl = smem + buf * 32768 + wave * 2048;
        char* gl = smem + buf * 32768 + 16384 + wave * 2048;
#pragma unroll
        for (int i = 0; i < 2; ++i) {
            gll16(phiSrc + (size_t)(koff + pk[i]) * 256 + pco[i], pl + i * 1024);
            gll16(gSrc + (size_t)(gr0 + i * 8) * 4096 + (size_t)koff * 2 + gu * 16, gl + i * 1024);
        }
    };

    f32x4 yacc[8];
#pragma unroll
    for (int c = 0; c < 8; ++c) yacc[c] = (f32x4){0.f, 0.f, 0.f, 0.f};
    float lreg = 0.f;

    STAGE(0, koff0);
    __syncthreads();

    char* pPb[2] = { smem + 65536 + wave * 1024, smem + 73728 + wave * 1024 };
    const int swq = (lq & 3) << 4;
    const int swk = (lq & 7) << 4;

    for (int ch = 0; ch < NCH; ++ch) {
        const int cur = ch & 1;
        if (ch < NCH - 1) STAGE(cur ^ 1, koff0 + (ch + 1) * KT);
        const char* pbuf = smem + cur * 32768;
        const char* gbuf = smem + cur * 32768 + 16384;

#pragma unroll
        for (int t2 = 0; t2 < 2; ++t2) {
            char* pP = pPb[t2];
            f32x4 sacc[2];
            sacc[0] = (f32x4){0.f, 0.f, 0.f, 0.f};
            sacc[1] = (f32x4){0.f, 0.f, 0.f, 0.f};
            __builtin_amdgcn_s_setprio(1);
#pragma unroll
            for (int D = 0; D < 4; ++D) {
                const int co = (((D * 4 + G) << 4) ^ swk);
                const bf16x8 a0 = *(const bf16x8*)(pbuf + (t2 * 32 + lq) * 256 + co);
                const bf16x8 a1 = *(const bf16x8*)(pbuf + (t2 * 32 + 16 + lq) * 256 + co);
                sacc[0] = __builtin_amdgcn_mfma_f32_16x16x32_bf16(a0, tf[D], sacc[0], 0, 0, 0);
                sacc[1] = __builtin_amdgcn_mfma_f32_16x16x32_bf16(a1, tf[D], sacc[1], 0, 0, 0);
            }
            __builtin_amdgcn_s_setprio(0);

            // p = exp(s - SUBC) = exp2(s*log2e - SUBC*log2e)  (fma + v_exp)
            float p[8];
#pragma unroll
            for (int ks = 0; ks < 2; ++ks)
#pragma unroll
                for (int r = 0; r < 4; ++r) {
                    const float e = exp2f(fmaf(sacc[ks][r], LOG2E, -SUBC * LOG2E));
                    p[ks * 4 + r] = e;
                    lreg += e;
                }
            // truncation pack (2 ops/pair; bias ~0.2% of P, cancels in y/l)
#pragma unroll
            for (int ks = 0; ks < 2; ++ks)
#pragma unroll
                for (int r2 = 0; r2 < 2; ++r2) {
                    const unsigned u0 = __builtin_bit_cast(unsigned, p[ks * 4 + r2 * 2]);
                    const unsigned u1 = __builtin_bit_cast(unsigned, p[ks * 4 + r2 * 2 + 1]);
                    const unsigned w = (u0 >> 16) | (u1 & 0xffff0000u);
                    const int byt = (ks * 32 + G * 8 + r2 * 4) ^ swq;
                    *(unsigned*)(pP + lq * 64 + byt) = w;
                }

            const bf16x8 pf = *(const bf16x8*)(pP + lq * 64 + ((G * 16) ^ swq));
            __builtin_amdgcn_s_setprio(1);
#pragma unroll
            for (int c = 0; c < 8; ++c) {
                const int row = c * 16 + lq;
                const bf16x8 gf = *(const bf16x8*)(gbuf + row * 128 + t2 * 64 +
                                                   ((G * 16) ^ ((row & 3) << 4)));
                yacc[c] = __builtin_amdgcn_mfma_f32_16x16x32_bf16(gf, pf, yacc[c], 0, 0, 0);
            }
            __builtin_amdgcn_s_setprio(0);
        }
        __syncthreads();
    }

    lreg += __shfl_xor(lreg, 16);
    lreg += __shfl_xor(lreg, 32);

    const int sb = b * NSPLIT + s;
    if (lane < 16) lbuf[(size_t)sb * NN + qbase + lq] = lreg;
    const size_t nrow = ((size_t)sb * NN + qbase + lq) * CI;
#pragma unroll
    for (int c = 0; c < 8; ++c) {
        unsigned short pkk[4];
#pragma unroll
        for (int r = 0; r < 4; ++r) pkk[r] = f2bfbits(yacc[c][r]);
        *(uint2*)&yp[nrow + c * 16 + G * 4] = *(uint2*)pkk;
    }
}

// ---------------------------------------------------------------------------
// K3: output conv, fused combine, bf16 MFMA split-W + BN partial sums.
// [R17/R18/R19, proven; y2 bf16 in ws]
// grid (128 nt of 64 n, 2 cot, 2 b), 256 thr
// ---------------------------------------------------------------------------
__global__ __launch_bounds__(256, 2) void k_outconv(
    const unsigned short* __restrict__ yp, const float* __restrict__ lbuf,
    const unsigned short* __restrict__ woh, const unsigned short* __restrict__ wol,
    const float* __restrict__ obias, unsigned short* __restrict__ y2,
    float* __restrict__ psum, float* __restrict__ psq)
{
    const int nt_ = blockIdx.x, cot = blockIdx.y, b = blockIdx.z;
    const int nb = nt_ * 64;
    const int tid = threadIdx.x, wave = tid >> 6, lane = tid & 63;
    const int lq = lane & 15, G = lane >> 4;
    const int corow = cot * 128 + wave * 32;

    float inv[4];
#pragma unroll
    for (int nt = 0; nt < 4; ++nt) {
        const int n = nb + nt * 16 + lq;
        float l = 0.f;
#pragma unroll
        for (int s = 0; s < NSPLIT; ++s) l += lbuf[(size_t)(b * NSPLIT + s) * NN + n];
        inv[nt] = 1.f / l;
    }

    f32x4 acc[2][4];
#pragma unroll
    for (int ot = 0; ot < 2; ++ot)
#pragma unroll
        for (int nt = 0; nt < 4; ++nt) acc[ot][nt] = (f32x4){0.f, 0.f, 0.f, 0.f};

#pragma unroll
    for (int kc = 0; kc < 4; ++kc) {
        bf16x8 wh[2], wl[2];
#pragma unroll
        for (int ot = 0; ot < 2; ++ot) {
            const size_t wr = (size_t)(corow + ot * 16 + lq) * CI + kc * 32 + G * 8;
            wh[ot] = *(const bf16x8*)(woh + wr);
            wl[ot] = *(const bf16x8*)(wol + wr);
        }
#pragma unroll
        for (int s = 0; s < NSPLIT; ++s) {
            const unsigned short* xrow = yp + ((size_t)(b * NSPLIT + s) * NN + nb) * CI;
            bf16x8 xf[4];
#pragma unroll
            for (int nt = 0; nt < 4; ++nt)
                xf[nt] = *(const bf16x8*)(xrow + (size_t)(nt * 16 + lq) * CI + kc * 32 + G * 8);
#pragma unroll
            for (int ot = 0; ot < 2; ++ot)
#pragma unroll
                for (int nt = 0; nt < 4; ++nt) {
                    acc[ot][nt] = __builtin_amdgcn_mfma_f32_16x16x32_bf16(wh[ot], xf[nt], acc[ot][nt], 0, 0, 0);
                    acc[ot][nt] = __builtin_amdgcn_mfma_f32_16x16x32_bf16(wl[ot], xf[nt], acc[ot][nt], 0, 0, 0);
                }
        }
    }

#pragma unroll
    for (int ot = 0; ot < 2; ++ot) {
        const float4 bv = *(const float4*)&obias[corow + ot * 16 + G * 4];
#pragma unroll
        for (int nt = 0; nt < 4; ++nt) {
            acc[ot][nt][0] = acc[ot][nt][0] * inv[nt] + bv.x;
            acc[ot][nt][1] = acc[ot][nt][1] * inv[nt] + bv.y;
            acc[ot][nt][2] = acc[ot][nt][2] * inv[nt] + bv.z;
            acc[ot][nt][3] = acc[ot][nt][3] * inv[nt] + bv.w;
        }
    }

    // y2 [b][co][n] bf16 (stats below use fp32 acc, unaffected by rounding)
#pragma unroll
    for (int ot = 0; ot < 2; ++ot)
#pragma unroll
        for (int r = 0; r < 4; ++r) {
            const int co = corow + ot * 16 + G * 4 + r;
            unsigned short* dst = &y2[((size_t)b * CC + co) * NN + nb + lq];
#pragma unroll
            for (int nt = 0; nt < 4; ++nt) dst[nt * 16] = f2bfbits(acc[ot][nt][r]);
        }

#pragma unroll
    for (int ot = 0; ot < 2; ++ot)
#pragma unroll
        for (int r = 0; r < 4; ++r) {
            float sv = 0.f, q = 0.f;
#pragma unroll
            for (int nt = 0; nt < 4; ++nt) {
                const float v = acc[ot][nt][r];
                sv += v; q += v * v;
            }
#pragma unroll
            for (int d = 1; d < 16; d <<= 1) { sv += __shfl_xor(sv, d); q += __shfl_xor(q, d); }
            if (lq == 0) {
                const int co = corow + ot * 16 + G * 4 + r;
                psum[co * 256 + b * 128 + nt_] = sv;
                psq [co * 256 + b * 128 + nt_] = q;
            }
        }
}

// ---------------------------------------------------------------------------
// K4: reduce partials -> mean, inv_std.  Parallel: grid (256) blocks,
// 256 thr, shuffle+LDS tree reduce.  [R19, proven]
// ---------------------------------------------------------------------------
__global__ __launch_bounds__(256) void k_red(
    const float* __restrict__ psum, const float* __restrict__ psq,
    float* __restrict__ stats)
{
    __shared__ float ssum[4], ssq[4];
    const int co = blockIdx.x;
    const int t = threadIdx.x;
    float s = psum[co * 256 + t];
    float q = psq [co * 256 + t];
#pragma unroll
    for (int d = 1; d < 64; d <<= 1) { s += __shfl_xor(s, d); q += __shfl_xor(q, d); }
    if ((t & 63) == 0) { ssum[t >> 6] = s; ssq[t >> 6] = q; }
    __syncthreads();
    if (t == 0) {
        const float st = ssum[0] + ssum[1] + ssum[2] + ssum[3];
        const float qt = ssq[0] + ssq[1] + ssq[2] + ssq[3];
        const float mean = st * (1.f / 16384.f);
        const float var = qt * (1.f / 16384.f) - mean * mean;
        stats[co] = mean;
        stats[256 + co] = rsqrtf(var + 1e-5f);
    }
}

// K5: out = x + bn(y2) ; y2 bf16 from ws, out fp32 to d_out
__global__ __launch_bounds__(256) void k_bn(
    const float* __restrict__ x, const unsigned short* __restrict__ y2,
    const float* __restrict__ bw, const float* __restrict__ bb,
    const float* __restrict__ stats, float* __restrict__ out)
{
    const int i4 = blockIdx.x * 256 + threadIdx.x;
    const int c = (i4 >> 11) & 255;
    const float a = stats[256 + c] * bw[c];
    const float bias2 = bb[c] - stats[c] * a;
    const uint2 v2 = ((const uint2*)y2)[i4];
    const float4 xv = ((const float4*)x)[i4];
    float4 r;
    r.x = xv.x + bf2f((unsigned short)(v2.x & 0xffff)) * a + bias2;
    r.y = xv.y + bf2f((unsigned short)(v2.x >> 16))    * a + bias2;
    r.z = xv.z + bf2f((unsigned short)(v2.y & 0xffff)) * a + bias2;
    r.w = xv.w + bf2f((unsigned short)(v2.y >> 16))    * a + bias2;
    ((float4*)out)[i4] = r;
}

extern "C" void kernel_launch(void* const* d_in, const int* in_sizes, int n_in,
                              void* d_out, int out_size, void* d_ws, size_t ws_size,
                              hipStream_t stream) {
    const float* x       = (const float*)d_in[0];
    const float* g_w     = (const float*)d_in[1];
    const float* g_b     = (const float*)d_in[2];
    const float* theta_w = (const float*)d_in[3];
    const float* theta_b = (const float*)d_in[4];
    const float* phi_w   = (const float*)d_in[5];
    const float* phi_b   = (const float*)d_in[6];
    const float* out_w   = (const float*)d_in[7];
    const float* out_b   = (const float*)d_in[8];
    const float* bn_w    = (const float*)d_in[9];
    const float* bn_b    = (const float*)d_in[10];

    char* ws = (char*)d_ws;
    unsigned short* wqh     = (unsigned short*)(ws + OFF_WQH);
    unsigned short* wql     = (unsigned short*)(ws + OFF_WQL);
    unsigned short* woh     = (unsigned short*)(ws + OFF_WOH);
    unsigned short* wol     = (unsigned short*)(ws + OFF_WOL);
    unsigned short* theta16 = (unsigned short*)(ws + OFF_THETA16);
    unsigned short* phi16   = (unsigned short*)(ws + OFF_PHI16);
    unsigned short* g16     = (unsigned short*)(ws + OFF_G16);
    unsigned short* yp      = (unsigned short*)(ws + OFF_YP);
    unsigned short* y2      = (unsigned short*)(ws + OFF_Y2);
    float* lbuf  = (float*)(ws + OFF_LBUF);
    float* psum  = (float*)(ws + OFF_PSUM);
    float* psq   = (float*)(ws + OFF_PSQ);
    float* stats = (float*)(ws + OFF_STAT);
    float* out   = (float*)d_out;

    k_prep<<<dim3(256), 512, 0, stream>>>(theta_w, phi_w, g_w, out_w, wqh, wql, woh, wol);
    k_fused<<<dim3(128, 2), 512, 0, stream>>>(x, wqh, wql, theta_b, phi_b, g_b,
                                              theta16, phi16, g16);
    k_attn<<<dim3(64, NSPLIT, 2), 512, 0, stream>>>(theta16, phi16, g16, yp, lbuf);
    k_outconv<<<dim3(128, 2, 2), 256, 0, stream>>>(yp, lbuf, woh, wol, out_b, y2, psum, psq);
    k_red<<<256, 256, 0, stream>>>(psum, psq, stats);
    k_bn<<<4096, 256, 0, stream>>>(x, y2, bn_w, bn_b, stats, out);
}